// Round 1
// baseline (2231.320 us; speedup 1.0000x reference)
//
#include <hip/hip_runtime.h>
#include <math.h>

// Phasor attention, fp32-faithful implementation.
// B=2, T=1024, D=512, H=8.
// Pipeline: proj(q/k/v) -> scores -> softmax -> PV -> final dense.
// All angles stored normalized (angle/pi), matching the numpy dataflow.

#define PI_F 3.14159274101257324f  // (float)pi, what jnp uses for f32

// encode 4 normalized angles -> cos/sin planes in LDS (k-major layout)
#define ENC4(vv, CP, SP, kq, m) do { \
    float c_, s_; \
    sincosf(PI_F*(vv).x, &s_, &c_); CP[(kq)+0][m]=c_; SP[(kq)+0][m]=s_; \
    sincosf(PI_F*(vv).y, &s_, &c_); CP[(kq)+1][m]=c_; SP[(kq)+1][m]=s_; \
    sincosf(PI_F*(vv).z, &s_, &c_); CP[(kq)+2][m]=c_; SP[(kq)+2][m]=s_; \
    sincosf(PI_F*(vv).w, &s_, &c_); CP[(kq)+3][m]=c_; SP[(kq)+3][m]=s_; \
} while (0)

// ---------------------------------------------------------------------------
// Projection: theta[b,h,t,n] = atan2( sum_d sin(pi x)w , sum_d cos(pi x)w + bias ) / pi
// x: [2048,512], w: [8,512,512], bias: [8,512], theta: [2,8,1024,512]
// BM=128, BN=64, BK=16, 256 threads, 8x4 per thread, re/im accumulators.
// ---------------------------------------------------------------------------
__global__ __launch_bounds__(256) void proj_gemm(
    const float* __restrict__ x, const float* __restrict__ w,
    const float* __restrict__ bias, float* __restrict__ theta)
{
    const int mt = blockIdx.x;   // 16 tiles of 128 over M=2048
    const int h  = blockIdx.y;   // 8 heads
    const int nt = blockIdx.z;   // 8 tiles of 64 over N=512 (within head)
    const int m0 = mt * 128, n0 = nt * 64;

    __shared__ float acs[16][132];
    __shared__ float ass[16][132];
    __shared__ float bss[16][68];

    const int tid = threadIdx.x;
    const int txm = tid & 15, txn = tid >> 4;

    float accr[8][4] = {{0.f}}, acci[8][4] = {{0.f}};

    for (int k0 = 0; k0 < 512; k0 += 16) {
        __syncthreads();
        // stage A (phasors of x): 128 m x 16 k
        #pragma unroll
        for (int r = 0; r < 2; ++r) {
            int f = tid + 256 * r;
            int m = f >> 2, kq = (f & 3) * 4;
            float4 xv = *reinterpret_cast<const float4*>(&x[(m0 + m) * 512 + k0 + kq]);
            ENC4(xv, acs, ass, kq, m);
        }
        // stage B (weights): 16 k x 64 n
        {
            int k = tid >> 4, nq = (tid & 15) * 4;
            float4 wv = *reinterpret_cast<const float4*>(&w[((h * 512) + k0 + k) * 512 + n0 + nq]);
            *reinterpret_cast<float4*>(&bss[k][nq]) = wv;
        }
        __syncthreads();
        #pragma unroll
        for (int k = 0; k < 16; ++k) {
            float4 a0 = *reinterpret_cast<const float4*>(&acs[k][txm * 4]);
            float4 a1 = *reinterpret_cast<const float4*>(&acs[k][64 + txm * 4]);
            float4 p0 = *reinterpret_cast<const float4*>(&ass[k][txm * 4]);
            float4 p1 = *reinterpret_cast<const float4*>(&ass[k][64 + txm * 4]);
            float4 bv = *reinterpret_cast<const float4*>(&bss[k][txn * 4]);
            float am[8] = {a0.x,a0.y,a0.z,a0.w,a1.x,a1.y,a1.z,a1.w};
            float sm[8] = {p0.x,p0.y,p0.z,p0.w,p1.x,p1.y,p1.z,p1.w};
            float bn[4] = {bv.x,bv.y,bv.z,bv.w};
            #pragma unroll
            for (int i = 0; i < 8; ++i)
                #pragma unroll
                for (int j = 0; j < 4; ++j) {
                    accr[i][j] = fmaf(am[i], bn[j], accr[i][j]);
                    acci[i][j] = fmaf(sm[i], bn[j], acci[i][j]);
                }
        }
    }
    #pragma unroll
    for (int i = 0; i < 8; ++i) {
        int ml = (i < 4) ? (txm * 4 + i) : (64 + txm * 4 + (i - 4));
        int mg = m0 + ml;
        int b = mg >> 10, t = mg & 1023;
        float* orow = &theta[(((b * 8 + h) * 1024) + t) * 512 + n0];
        #pragma unroll
        for (int j = 0; j < 4; ++j) {
            int n = txn * 4 + j;
            float yr = accr[i][j] + bias[h * 512 + n0 + n];
            float yi = acci[i][j];
            orow[n] = atan2f(yi, yr) / PI_F;
        }
    }
}

// ---------------------------------------------------------------------------
// Scores: S[bh,t,T] = (sum_d qc*kc + qs*ks) / 512
// BM=BN=128, BK=16, 256 threads, 8x8 per thread.
// ---------------------------------------------------------------------------
__global__ __launch_bounds__(256) void scores_gemm(
    const float* __restrict__ thq, const float* __restrict__ thk,
    float* __restrict__ S)
{
    const int mt = blockIdx.x;   // 8 tiles of 128 (q rows)
    const int nt = blockIdx.y;   // 8 tiles of 128 (k rows)
    const int bh = blockIdx.z;   // 16
    const int m0 = mt * 128, n0 = nt * 128;

    __shared__ float qc[16][132], qs[16][132], kc[16][132], ks[16][132];

    const int tid = threadIdx.x;
    const int txm = tid & 15, txn = tid >> 4;
    const float* qb = thq + (size_t)bh * 1024 * 512;
    const float* kb = thk + (size_t)bh * 1024 * 512;

    float acc[8][8] = {{0.f}};

    for (int k0 = 0; k0 < 512; k0 += 16) {
        __syncthreads();
        #pragma unroll
        for (int r = 0; r < 2; ++r) {
            int f = tid + 256 * r;
            int m = f >> 2, kq = (f & 3) * 4;
            float4 qv = *reinterpret_cast<const float4*>(&qb[(m0 + m) * 512 + k0 + kq]);
            ENC4(qv, qc, qs, kq, m);
            float4 kv = *reinterpret_cast<const float4*>(&kb[(n0 + m) * 512 + k0 + kq]);
            ENC4(kv, kc, ks, kq, m);
        }
        __syncthreads();
        #pragma unroll
        for (int k = 0; k < 16; ++k) {
            float4 a0 = *reinterpret_cast<const float4*>(&qc[k][txm * 4]);
            float4 a1 = *reinterpret_cast<const float4*>(&qc[k][64 + txm * 4]);
            float4 s0 = *reinterpret_cast<const float4*>(&qs[k][txm * 4]);
            float4 s1 = *reinterpret_cast<const float4*>(&qs[k][64 + txm * 4]);
            float4 b0 = *reinterpret_cast<const float4*>(&kc[k][txn * 4]);
            float4 b1 = *reinterpret_cast<const float4*>(&kc[k][64 + txn * 4]);
            float4 t0 = *reinterpret_cast<const float4*>(&ks[k][txn * 4]);
            float4 t1 = *reinterpret_cast<const float4*>(&ks[k][64 + txn * 4]);
            float am[8] = {a0.x,a0.y,a0.z,a0.w,a1.x,a1.y,a1.z,a1.w};
            float sm[8] = {s0.x,s0.y,s0.z,s0.w,s1.x,s1.y,s1.z,s1.w};
            float bn[8] = {b0.x,b0.y,b0.z,b0.w,b1.x,b1.y,b1.z,b1.w};
            float tn[8] = {t0.x,t0.y,t0.z,t0.w,t1.x,t1.y,t1.z,t1.w};
            #pragma unroll
            for (int i = 0; i < 8; ++i)
                #pragma unroll
                for (int j = 0; j < 8; ++j) {
                    acc[i][j] = fmaf(am[i], bn[j], acc[i][j]);
                    acc[i][j] = fmaf(sm[i], tn[j], acc[i][j]);
                }
        }
    }
    const float inv_d = 1.0f / 512.0f;  // exact (power of two)
    #pragma unroll
    for (int i = 0; i < 8; ++i) {
        int ml = (i < 4) ? (txm * 4 + i) : (64 + txm * 4 + (i - 4));
        float* srow = &S[((size_t)bh * 1024 + (m0 + ml)) * 1024 + n0];
        #pragma unroll
        for (int j = 0; j < 8; ++j) {
            int nl = (j < 4) ? (txn * 4 + j) : (64 + txn * 4 + (j - 4));
            srow[nl] = acc[i][j] * inv_d;
        }
    }
}

// ---------------------------------------------------------------------------
// Row softmax in place (rows of 1024), max-subtracted like jax.nn.softmax.
// ---------------------------------------------------------------------------
__global__ __launch_bounds__(256) void softmax_rows(float* __restrict__ S)
{
    const int row = blockIdx.x;  // 16384
    float* p = S + (size_t)row * 1024;
    const int tid = threadIdx.x;
    float4 v = *reinterpret_cast<const float4*>(&p[tid * 4]);
    float m = fmaxf(fmaxf(v.x, v.y), fmaxf(v.z, v.w));
    #pragma unroll
    for (int off = 32; off >= 1; off >>= 1)
        m = fmaxf(m, __shfl_xor(m, off));
    __shared__ float redm[4];
    __shared__ float reds[4];
    const int wid = tid >> 6, lane = tid & 63;
    if (lane == 0) redm[wid] = m;
    __syncthreads();
    m = fmaxf(fmaxf(redm[0], redm[1]), fmaxf(redm[2], redm[3]));
    float4 e;
    e.x = expf(v.x - m); e.y = expf(v.y - m);
    e.z = expf(v.z - m); e.w = expf(v.w - m);
    float s = (e.x + e.y) + (e.z + e.w);
    #pragma unroll
    for (int off = 32; off >= 1; off >>= 1)
        s += __shfl_xor(s, off);
    if (lane == 0) reds[wid] = s;
    __syncthreads();
    s = (reds[0] + reds[1]) + (reds[2] + reds[3]);
    e.x /= s; e.y /= s; e.z /= s; e.w /= s;
    *reinterpret_cast<float4*>(&p[tid * 4]) = e;
}

// ---------------------------------------------------------------------------
// PV: out[bh,t,d] = sum_T P[t,T] * exp(i*pi*thv[T,d]); r = angle/pi -> rout
// BM=128, BN=64, BK=16, 256 threads, 8x4 per thread, re/im accumulators.
// ---------------------------------------------------------------------------
__global__ __launch_bounds__(256) void pv_gemm(
    const float* __restrict__ P, const float* __restrict__ thv,
    float* __restrict__ rout)
{
    const int mt = blockIdx.x;   // 8 tiles of 128 (t)
    const int nt = blockIdx.y;   // 8 tiles of 64 (d)
    const int bh = blockIdx.z;   // 16
    const int m0 = mt * 128, n0 = nt * 64;

    __shared__ float ap[16][132];
    __shared__ float vc[16][68], vs[16][68];

    const int tid = threadIdx.x;
    const int txm = tid & 15, txn = tid >> 4;
    const float* Pb = P + (size_t)bh * 1024 * 1024;
    const float* vb = thv + (size_t)bh * 1024 * 512;

    float accr[8][4] = {{0.f}}, acci[8][4] = {{0.f}};

    for (int k0 = 0; k0 < 1024; k0 += 16) {
        __syncthreads();
        // stage A (probs): 128 m x 16 k
        #pragma unroll
        for (int r = 0; r < 2; ++r) {
            int f = tid + 256 * r;
            int m = f >> 2, kq = (f & 3) * 4;
            float4 pv = *reinterpret_cast<const float4*>(&Pb[(size_t)(m0 + m) * 1024 + k0 + kq]);
            ap[kq + 0][m] = pv.x; ap[kq + 1][m] = pv.y;
            ap[kq + 2][m] = pv.z; ap[kq + 3][m] = pv.w;
        }
        // stage B (v phasors): 16 k x 64 n
        {
            int k = tid >> 4, nq = (tid & 15) * 4;
            float4 tv = *reinterpret_cast<const float4*>(&vb[(k0 + k) * 512 + n0 + nq]);
            float c_, s_;
            sincosf(PI_F * tv.x, &s_, &c_); vc[k][nq + 0] = c_; vs[k][nq + 0] = s_;
            sincosf(PI_F * tv.y, &s_, &c_); vc[k][nq + 1] = c_; vs[k][nq + 1] = s_;
            sincosf(PI_F * tv.z, &s_, &c_); vc[k][nq + 2] = c_; vs[k][nq + 2] = s_;
            sincosf(PI_F * tv.w, &s_, &c_); vc[k][nq + 3] = c_; vs[k][nq + 3] = s_;
        }
        __syncthreads();
        #pragma unroll
        for (int k = 0; k < 16; ++k) {
            float4 a0 = *reinterpret_cast<const float4*>(&ap[k][txm * 4]);
            float4 a1 = *reinterpret_cast<const float4*>(&ap[k][64 + txm * 4]);
            float4 bc = *reinterpret_cast<const float4*>(&vc[k][txn * 4]);
            float4 bs4 = *reinterpret_cast<const float4*>(&vs[k][txn * 4]);
            float am[8] = {a0.x,a0.y,a0.z,a0.w,a1.x,a1.y,a1.z,a1.w};
            float cn[4] = {bc.x,bc.y,bc.z,bc.w};
            float sn[4] = {bs4.x,bs4.y,bs4.z,bs4.w};
            #pragma unroll
            for (int i = 0; i < 8; ++i)
                #pragma unroll
                for (int j = 0; j < 4; ++j) {
                    accr[i][j] = fmaf(am[i], cn[j], accr[i][j]);
                    acci[i][j] = fmaf(am[i], sn[j], acci[i][j]);
                }
        }
    }
    #pragma unroll
    for (int i = 0; i < 8; ++i) {
        int ml = (i < 4) ? (txm * 4 + i) : (64 + txm * 4 + (i - 4));
        float* orow = &rout[((size_t)bh * 1024 + (m0 + ml)) * 512 + n0];
        #pragma unroll
        for (int j = 0; j < 4; ++j) {
            int n = txn * 4 + j;
            orow[n] = atan2f(acci[i][j], accr[i][j]) / PI_F;
        }
    }
}

// ---------------------------------------------------------------------------
// Final dense: out[m,n] = atan2( sum_k sin(pi r)wo , sum_k cos(pi r)wo + bo ) / pi
// m=(b,t) in 2048, k=(h,d) in 4096, n in 512. BM=BN=64, BK=16, 4x4/thread.
// ---------------------------------------------------------------------------
__global__ __launch_bounds__(256) void final_gemm(
    const float* __restrict__ rth, const float* __restrict__ wo,
    const float* __restrict__ bo, float* __restrict__ out)
{
    const int mt = blockIdx.x;   // 32 tiles of 64 over M=2048
    const int nt = blockIdx.y;   // 8 tiles of 64 over N=512
    const int m0 = mt * 64, n0 = nt * 64;

    __shared__ float ac_[16][68], as_[16][68], bs_[16][68];

    const int tid = threadIdx.x;
    const int txm = tid & 15, txn = tid >> 4;

    float accr[4][4] = {{0.f}}, acci[4][4] = {{0.f}};

    for (int k0 = 0; k0 < 4096; k0 += 16) {
        __syncthreads();
        // stage A (phasors of r): 64 m x 16 k; k=(h,d), float4 stays within one h
        {
            int m = tid >> 2, kq = (tid & 3) * 4;
            int mg = m0 + m;
            int b = mg >> 10, t = mg & 1023;
            int k = k0 + kq;
            int h = k >> 9, d = k & 511;
            float4 rv = *reinterpret_cast<const float4*>(&rth[(((b * 8 + h) * 1024) + t) * 512 + d]);
            ENC4(rv, ac_, as_, kq, m);
        }
        // stage B (wo): 16 k x 64 n
        {
            int k = tid >> 4, nq = (tid & 15) * 4;
            float4 wv = *reinterpret_cast<const float4*>(&wo[(k0 + k) * 512 + n0 + nq]);
            *reinterpret_cast<float4*>(&bs_[k][nq]) = wv;
        }
        __syncthreads();
        #pragma unroll
        for (int k = 0; k < 16; ++k) {
            float4 a0 = *reinterpret_cast<const float4*>(&ac_[k][txm * 4]);
            float4 s0 = *reinterpret_cast<const float4*>(&as_[k][txm * 4]);
            float4 bv = *reinterpret_cast<const float4*>(&bs_[k][txn * 4]);
            float am[4] = {a0.x,a0.y,a0.z,a0.w};
            float sm[4] = {s0.x,s0.y,s0.z,s0.w};
            float bn[4] = {bv.x,bv.y,bv.z,bv.w};
            #pragma unroll
            for (int i = 0; i < 4; ++i)
                #pragma unroll
                for (int j = 0; j < 4; ++j) {
                    accr[i][j] = fmaf(am[i], bn[j], accr[i][j]);
                    acci[i][j] = fmaf(sm[i], bn[j], acci[i][j]);
                }
        }
    }
    #pragma unroll
    for (int i = 0; i < 4; ++i) {
        int mg = m0 + txm * 4 + i;
        float* orow = &out[(size_t)mg * 512 + n0];
        #pragma unroll
        for (int j = 0; j < 4; ++j) {
            int n = txn * 4 + j;
            float zr = accr[i][j] + bo[n0 + n];
            float zi = acci[i][j];
            orow[n] = atan2f(zi, zr) / PI_F;
        }
    }
}

// ---------------------------------------------------------------------------
extern "C" void kernel_launch(void* const* d_in, const int* in_sizes, int n_in,
                              void* d_out, int out_size, void* d_ws, size_t ws_size,
                              hipStream_t stream)
{
    (void)in_sizes; (void)n_in; (void)out_size; (void)ws_size;
    const float* query    = (const float*)d_in[0];
    const float* keyvalue = (const float*)d_in[1];
    const float* wq = (const float*)d_in[2];
    const float* bq = (const float*)d_in[3];
    const float* wk = (const float*)d_in[4];
    const float* bk = (const float*)d_in[5];
    const float* wv = (const float*)d_in[6];
    const float* bv = (const float*)d_in[7];
    const float* wo = (const float*)d_in[8];
    const float* bo = (const float*)d_in[9];
    float* out = (float*)d_out;
    float* ws  = (float*)d_ws;

    // ws layout (floats): thq 8.4M | thk 8.4M | thv 8.4M | S 16.8M  => 160 MB
    float* thq = ws;
    float* thk = ws + 8388608;
    float* thv = ws + 16777216;
    float* S   = ws + 25165824;

    dim3 blk(256);
    hipLaunchKernelGGL(proj_gemm, dim3(16, 8, 8), blk, 0, stream, query,    wq, bq, thq);
    hipLaunchKernelGGL(proj_gemm, dim3(16, 8, 8), blk, 0, stream, keyvalue, wk, bk, thk);
    hipLaunchKernelGGL(proj_gemm, dim3(16, 8, 8), blk, 0, stream, keyvalue, wv, bv, thv);
    hipLaunchKernelGGL(scores_gemm, dim3(8, 8, 16), blk, 0, stream, thq, thk, S);
    hipLaunchKernelGGL(softmax_rows, dim3(16384), blk, 0, stream, S);
    // PV writes r in place over thq (thq fully consumed by scores_gemm already)
    hipLaunchKernelGGL(pv_gemm, dim3(8, 8, 16), blk, 0, stream, S, thv, thq);
    hipLaunchKernelGGL(final_gemm, dim3(32, 8), blk, 0, stream, thq, wo, bo, out);
}

// Round 2
// 758.324 us; speedup vs baseline: 2.9424x; 2.9424x over previous
//
#include <hip/hip_runtime.h>
#include <math.h>

// Phasor attention via split-fp16 MFMA (fp16x2 error-free splitting, ~fp32 accuracy).
// B=2, T=1024, D=512, H=8.
// Pipeline: encode -> proj(q/k/v) -> scores -> softmax -> PV -> final dense.
// All intermediate phasors stored normalized (c,s) as fp16 hi/lo plane pairs
// (lo pre-scaled by 2^12 so it never hits fp16 denormals in MFMA).

#define PI_F 3.14159274101257324f

typedef __attribute__((ext_vector_type(8))) _Float16 half8;
typedef __attribute__((ext_vector_type(4))) _Float16 half4;
typedef __attribute__((ext_vector_type(2))) _Float16 half2v;
typedef __attribute__((ext_vector_type(4))) float f32x4;
typedef unsigned int u32;

#define MFMA16(a, b, c) __builtin_amdgcn_mfma_f32_16x16x32_f16((a), (b), (c), 0, 0, 0)

__device__ __forceinline__ void gll16(const void* g, void* l) {
    __builtin_amdgcn_global_load_lds(
        (const __attribute__((address_space(1))) u32*)g,
        (__attribute__((address_space(3))) u32*)l, 16, 0, 0);
}

// Stage R rows x 64 fp16 (128B/row) into LDS; 16B-slot XOR swizzle (slot ^= row&7)
// applied on the PRE-SWIZZLED global source (LDS dest stays linear). 256 threads.
template<int R>
__device__ __forceinline__ void stageT(char* ldsp, const _Float16* g, int strideE) {
    const int tid = threadIdx.x;
    const int wv = tid >> 6, ln = tid & 63;
    const int mr = ln >> 3, slot = ln & 7;
#pragma unroll
    for (int ci = 0; ci < R / 32; ++ci) {
        const int c = wv + ci * 4;
        const int m = c * 8 + mr;
        const char* src = (const char*)(g + (size_t)m * strideE) + ((slot ^ (m & 7)) << 4);
        gll16(src, ldsp + c * 1024);
    }
}

// Fragment load: 8 consecutive k fp16 for row, with matching XOR de-swizzle.
__device__ __forceinline__ half8 fragld(const char* ldsp, int row, int kslot) {
    return *(const half8*)(ldsp + row * 128 + (((kslot ^ (row & 7))) << 4));
}

__device__ __forceinline__ void split2(float x, _Float16& h, _Float16& l) {
    _Float16 hh = (_Float16)x;
    h = hh;
    l = (_Float16)((x - (float)hh) * 4096.0f);
}

// ---------------------------------------------------------------------------
// encode: x [2048*512] f32 -> phasor planes cos/sin hi/lo [2048][512] fp16.
// ---------------------------------------------------------------------------
__global__ __launch_bounds__(256) void encode_phasor(
    const float* __restrict__ x,
    _Float16* __restrict__ ch, _Float16* __restrict__ cl,
    _Float16* __restrict__ sh, _Float16* __restrict__ sl)
{
    const int idx = blockIdx.x * 256 + threadIdx.x;  // one float4 each; grid exact
    float4 v = ((const float4*)x)[idx];
    float cc[4], ss[4];
    sincosf(PI_F * v.x, &ss[0], &cc[0]);
    sincosf(PI_F * v.y, &ss[1], &cc[1]);
    sincosf(PI_F * v.z, &ss[2], &cc[2]);
    sincosf(PI_F * v.w, &ss[3], &cc[3]);
    half4 chv, clv, shv, slv;
#pragma unroll
    for (int q = 0; q < 4; ++q) {
        _Float16 a, b;
        split2(cc[q], a, b); chv[q] = a; clv[q] = b;
        split2(ss[q], a, b); shv[q] = a; slv[q] = b;
    }
    ((half4*)ch)[idx] = chv;
    ((half4*)cl)[idx] = clv;
    ((half4*)sh)[idx] = shv;
    ((half4*)sl)[idx] = slv;
}

// ---------------------------------------------------------------------------
// tsplit64: w [h][K][N] f32 -> transposed split planes th/tl [h][N][K] fp16.
// ---------------------------------------------------------------------------
__global__ __launch_bounds__(256) void tsplit64(
    const float* __restrict__ w, _Float16* __restrict__ th, _Float16* __restrict__ tl,
    int K, int N)
{
    const int kt = blockIdx.x, ntile = blockIdx.y, h = blockIdx.z;
    const int k0 = kt * 64, n0 = ntile * 64;
    __shared__ float T[64][65];
    const int tid = threadIdx.x;
    const float* wb = w + (size_t)h * K * N;
    {
        const int r = tid >> 4, c4 = (tid & 15) * 4;
#pragma unroll
        for (int rr = 0; rr < 64; rr += 16) {
            float4 v = *(const float4*)&wb[(size_t)(k0 + rr + r) * N + n0 + c4];
            T[rr + r][c4 + 0] = v.x; T[rr + r][c4 + 1] = v.y;
            T[rr + r][c4 + 2] = v.z; T[rr + r][c4 + 3] = v.w;
        }
    }
    __syncthreads();
    {
        const int n = tid >> 2, kq = (tid & 3) * 16;
        half8 hv[2], lv[2];
#pragma unroll
        for (int q = 0; q < 16; ++q) {
            float f = T[kq + q][n];
            _Float16 hh, ll; split2(f, hh, ll);
            hv[q >> 3][q & 7] = hh; lv[q >> 3][q & 7] = ll;
        }
        _Float16* oh = th + ((size_t)h * N + n0 + n) * K + k0 + kq;
        _Float16* ol = tl + ((size_t)h * N + n0 + n) * K + k0 + kq;
        *(half8*)oh = hv[0]; *(half8*)(oh + 8) = hv[1];
        *(half8*)ol = lv[0]; *(half8*)(ol + 8) = lv[1];
    }
}

// ---------------------------------------------------------------------------
// proj: y = phasor(x) @ w + bias -> normalize -> split planes.
// A: xc/xs hi/lo [2048][512]; B: wT hi/lo [hcnt][512][512] (n-major).
// VT=0: write qz interleaved (c,s) planes [2*hcnt][1024][1024] hi/lo.
// VT=1: write vT planes [2*hcnt][512][1024] (d-major) via LDS transpose.
// Block 128x64, 4 waves (2x2), wave tile 64x32, K=512.
// ---------------------------------------------------------------------------
template<bool VT>
__global__ __launch_bounds__(256, 2) void proj_mfma(
    const _Float16* __restrict__ xch, const _Float16* __restrict__ xcl,
    const _Float16* __restrict__ xsh, const _Float16* __restrict__ xsl,
    const _Float16* __restrict__ wth, const _Float16* __restrict__ wtl,
    const float* __restrict__ bias,
    _Float16* __restrict__ o0h, _Float16* __restrict__ o0l,
    _Float16* __restrict__ vch, _Float16* __restrict__ vcl,
    _Float16* __restrict__ vsh, _Float16* __restrict__ vsl,
    int h0, int hcnt)
{
    const int mt = blockIdx.x;
    const int hc = blockIdx.y >> 3;
    const int nt = blockIdx.y & 7;
    const int m0 = mt * 128, n0 = nt * 64;
    __shared__ char lds[81920];
    char* Ach = lds;
    char* Acl = lds + 16384;
    char* Ash = lds + 32768;
    char* Asl = lds + 49152;
    char* Bh  = lds + 65536;
    char* Bl  = lds + 73728;
    const int tid = threadIdx.x, wv = tid >> 6, ln = tid & 63;
    const int wr = wv >> 1, wc = wv & 1, lm = ln & 15, lk = ln >> 4;

    f32x4 ach_[4][2] = {}, acl_[4][2] = {}, ash_[4][2] = {}, asl_[4][2] = {};
    const _Float16* wbh = wth + ((size_t)hc * 512 + n0) * 512;
    const _Float16* wbl = wtl + ((size_t)hc * 512 + n0) * 512;

    for (int k0 = 0; k0 < 512; k0 += 64) {
        __syncthreads();
        stageT<128>(Ach, xch + (size_t)m0 * 512 + k0, 512);
        stageT<128>(Acl, xcl + (size_t)m0 * 512 + k0, 512);
        stageT<128>(Ash, xsh + (size_t)m0 * 512 + k0, 512);
        stageT<128>(Asl, xsl + (size_t)m0 * 512 + k0, 512);
        stageT<64>(Bh, wbh + k0, 512);
        stageT<64>(Bl, wbl + k0, 512);
        __syncthreads();
#pragma unroll
        for (int ks = 0; ks < 2; ++ks) {
            half8 bhf[2], blf[2];
#pragma unroll
            for (int j = 0; j < 2; ++j) {
                bhf[j] = fragld(Bh, wc * 32 + j * 16 + lm, ks * 4 + lk);
                blf[j] = fragld(Bl, wc * 32 + j * 16 + lm, ks * 4 + lk);
            }
#pragma unroll
            for (int i = 0; i < 4; ++i) {
                const int am = wr * 64 + i * 16 + lm;
                half8 a1 = fragld(Ach, am, ks * 4 + lk);
                half8 a2 = fragld(Acl, am, ks * 4 + lk);
                half8 a3 = fragld(Ash, am, ks * 4 + lk);
                half8 a4 = fragld(Asl, am, ks * 4 + lk);
#pragma unroll
                for (int j = 0; j < 2; ++j) {
                    ach_[i][j] = MFMA16(a1, bhf[j], ach_[i][j]);
                    acl_[i][j] = MFMA16(a1, blf[j], acl_[i][j]);
                    acl_[i][j] = MFMA16(a2, bhf[j], acl_[i][j]);
                    ash_[i][j] = MFMA16(a3, bhf[j], ash_[i][j]);
                    asl_[i][j] = MFMA16(a3, blf[j], asl_[i][j]);
                    asl_[i][j] = MFMA16(a4, bhf[j], asl_[i][j]);
                }
            }
        }
    }

    const float LS = 1.0f / 4096.0f;
    if constexpr (!VT) {
#pragma unroll
        for (int j = 0; j < 2; ++j) {
            const int nloc = wc * 32 + j * 16 + lm;
            const float bval = bias[(size_t)(h0 + hc) * 512 + n0 + nloc];
#pragma unroll
            for (int i = 0; i < 4; ++i)
#pragma unroll
                for (int r = 0; r < 4; ++r) {
                    const int mloc = wr * 64 + i * 16 + lk * 4 + r;
                    float yc = ach_[i][j][r] + acl_[i][j][r] * LS + bval;
                    float ys = ash_[i][j][r] + asl_[i][j][r] * LS;
                    float inv = 1.0f / sqrtf(fmaxf(yc * yc + ys * ys, 1e-36f));
                    float c = yc * inv, s = ys * inv;
                    _Float16 chh, chl, shh, shl;
                    split2(c, chh, chl); split2(s, shh, shl);
                    const int mg = m0 + mloc;
                    const int b = mg >> 10, t = mg & 1023;
                    const size_t z = (size_t)(b * hcnt + hc);
                    const size_t off = (z * 1024 + t) * 1024 + 2 * (n0 + nloc);
                    half2v hv, lv;
                    hv[0] = chh; hv[1] = shh; lv[0] = chl; lv[1] = shl;
                    *(half2v*)(o0h + off) = hv;
                    *(half2v*)(o0l + off) = lv;
                }
        }
    } else {
        // transpose epilogue: LDS [64 d][132 t-stride] per plane, then coalesced write
        __syncthreads();
        _Float16* T0 = (_Float16*)lds;
        _Float16* T1 = T0 + 64 * 132;
        _Float16* T2 = T1 + 64 * 132;
        _Float16* T3 = T2 + 64 * 132;
#pragma unroll
        for (int j = 0; j < 2; ++j) {
            const int dloc = wc * 32 + j * 16 + lm;
            const float bval = bias[(size_t)(h0 + hc) * 512 + n0 + dloc];
#pragma unroll
            for (int i = 0; i < 4; ++i)
#pragma unroll
                for (int r = 0; r < 4; ++r) {
                    const int tloc = wr * 64 + i * 16 + lk * 4 + r;
                    float yc = ach_[i][j][r] + acl_[i][j][r] * LS + bval;
                    float ys = ash_[i][j][r] + asl_[i][j][r] * LS;
                    float inv = 1.0f / sqrtf(fmaxf(yc * yc + ys * ys, 1e-36f));
                    float c = yc * inv, s = ys * inv;
                    _Float16 chh, chl, shh, shl;
                    split2(c, chh, chl); split2(s, shh, shl);
                    T0[dloc * 132 + tloc] = chh;
                    T1[dloc * 132 + tloc] = chl;
                    T2[dloc * 132 + tloc] = shh;
                    T3[dloc * 132 + tloc] = shl;
                }
        }
        __syncthreads();
        const int pl = tid >> 6, d = tid & 63;
        const _Float16* Tp = T0 + (size_t)pl * 64 * 132 + d * 132;
        _Float16* outp;
        if (pl == 0) outp = vch; else if (pl == 1) outp = vcl;
        else if (pl == 2) outp = vsh; else outp = vsl;
        const int b = m0 >> 10, t0 = m0 & 1023;
        const size_t z = (size_t)(b * hcnt + hc);
        outp += (z * 512 + (size_t)(n0 + d)) * 1024 + t0;
#pragma unroll
        for (int q = 0; q < 32; ++q)
            *(half4*)(outp + q * 4) = *(const half4*)(Tp + q * 4);
    }
}

// ---------------------------------------------------------------------------
// scores: S[z][t][T] = (qz . kz)/512, qz/kz (c,s)-interleaved K=1024.
// Block 128x128, 4 waves (2x2), wave tile 64x64.
// ---------------------------------------------------------------------------
__global__ __launch_bounds__(256, 2) void scores_mfma(
    const _Float16* __restrict__ qzh, const _Float16* __restrict__ qzl,
    const _Float16* __restrict__ kzh, const _Float16* __restrict__ kzl,
    float* __restrict__ S)
{
    const int mt = blockIdx.x, nt = blockIdx.y, z = blockIdx.z;
    const int m0 = mt * 128, n0 = nt * 128;
    __shared__ char lds[65536];
    char* Ah = lds;
    char* Al = lds + 16384;
    char* Bh = lds + 32768;
    char* Bl = lds + 49152;
    const size_t zb = (size_t)z << 20;
    const int tid = threadIdx.x, wv = tid >> 6, ln = tid & 63;
    const int wr = wv >> 1, wc = wv & 1, lm = ln & 15, lk = ln >> 4;
    f32x4 acch[4][4] = {}, accl[4][4] = {};
    const _Float16* qh = qzh + zb + (size_t)m0 * 1024;
    const _Float16* ql = qzl + zb + (size_t)m0 * 1024;
    const _Float16* kh = kzh + zb + (size_t)n0 * 1024;
    const _Float16* kl = kzl + zb + (size_t)n0 * 1024;

    for (int k0 = 0; k0 < 1024; k0 += 64) {
        __syncthreads();
        stageT<128>(Ah, qh + k0, 1024);
        stageT<128>(Al, ql + k0, 1024);
        stageT<128>(Bh, kh + k0, 1024);
        stageT<128>(Bl, kl + k0, 1024);
        __syncthreads();
#pragma unroll
        for (int ks = 0; ks < 2; ++ks) {
            half8 bhf[4], blf[4];
#pragma unroll
            for (int j = 0; j < 4; ++j) {
                bhf[j] = fragld(Bh, wc * 64 + j * 16 + lm, ks * 4 + lk);
                blf[j] = fragld(Bl, wc * 64 + j * 16 + lm, ks * 4 + lk);
            }
#pragma unroll
            for (int i = 0; i < 4; ++i) {
                half8 ah = fragld(Ah, wr * 64 + i * 16 + lm, ks * 4 + lk);
                half8 al = fragld(Al, wr * 64 + i * 16 + lm, ks * 4 + lk);
#pragma unroll
                for (int j = 0; j < 4; ++j) {
                    acch[i][j] = MFMA16(ah, bhf[j], acch[i][j]);
                    accl[i][j] = MFMA16(ah, blf[j], accl[i][j]);
                    accl[i][j] = MFMA16(al, bhf[j], accl[i][j]);
                }
            }
        }
    }
    const float LS = 1.0f / 4096.0f, SC = 1.0f / 512.0f;
#pragma unroll
    for (int i = 0; i < 4; ++i)
#pragma unroll
        for (int j = 0; j < 4; ++j)
#pragma unroll
            for (int r = 0; r < 4; ++r) {
                const int row = m0 + wr * 64 + i * 16 + lk * 4 + r;
                const int col = n0 + wc * 64 + j * 16 + lm;
                S[zb + (size_t)row * 1024 + col] =
                    (acch[i][j][r] + accl[i][j][r] * LS) * SC;
            }
}

// ---------------------------------------------------------------------------
// softmax rows of 1024 (max-subtracted), write P as fp16 hi/lo split in-place:
// row reinterpreted as 2048 fp16: [0..1023]=hi, [1024..2047]=lo (lo scaled 2^12).
// ---------------------------------------------------------------------------
__global__ __launch_bounds__(256) void softmax_split(float* __restrict__ S)
{
    const size_t row = blockIdx.x;
    float* p = S + row * 1024;
    const int tid = threadIdx.x;
    float4 v = ((const float4*)p)[tid];
    float m = fmaxf(fmaxf(v.x, v.y), fmaxf(v.z, v.w));
#pragma unroll
    for (int off = 32; off >= 1; off >>= 1)
        m = fmaxf(m, __shfl_xor(m, off));
    __shared__ float redm[4], reds[4];
    const int wid = tid >> 6, lane = tid & 63;
    if (lane == 0) redm[wid] = m;
    __syncthreads();
    m = fmaxf(fmaxf(redm[0], redm[1]), fmaxf(redm[2], redm[3]));
    float4 e;
    e.x = expf(v.x - m); e.y = expf(v.y - m);
    e.z = expf(v.z - m); e.w = expf(v.w - m);
    float s = (e.x + e.y) + (e.z + e.w);
#pragma unroll
    for (int off = 32; off >= 1; off >>= 1)
        s += __shfl_xor(s, off);
    if (lane == 0) reds[wid] = s;
    __syncthreads();
    s = (reds[0] + reds[1]) + (reds[2] + reds[3]);
    e.x /= s; e.y /= s; e.z /= s; e.w /= s;
    __syncthreads();  // all reads of this row complete before fp16 overwrite
    _Float16* ph = (_Float16*)p;
    half4 hv, lv;
    _Float16 a, b;
    split2(e.x, a, b); hv[0] = a; lv[0] = b;
    split2(e.y, a, b); hv[1] = a; lv[1] = b;
    split2(e.z, a, b); hv[2] = a; lv[2] = b;
    split2(e.w, a, b); hv[3] = a; lv[3] = b;
    *(half4*)(ph + tid * 4) = hv;
    *(half4*)(ph + 1024 + tid * 4) = lv;
}

// ---------------------------------------------------------------------------
// pv: out[z][t][d] = sum_T P[t][T] * vz[T][d] (complex), normalize, split,
// write rc/rs planes [2048][4096] (k = h*512+d). Block 128x64, wave 64x32.
// ---------------------------------------------------------------------------
__global__ __launch_bounds__(256, 2) void pv_mfma(
    const _Float16* __restrict__ P,
    const _Float16* __restrict__ vch, const _Float16* __restrict__ vcl,
    const _Float16* __restrict__ vsh, const _Float16* __restrict__ vsl,
    _Float16* __restrict__ rch, _Float16* __restrict__ rcl,
    _Float16* __restrict__ rsh, _Float16* __restrict__ rsl,
    int h0, int hcnt)
{
    const int mt = blockIdx.x, nt = blockIdx.y, z = blockIdx.z;
    const int m0 = mt * 128, n0 = nt * 64;
    __shared__ char lds[65536];
    char* Ah  = lds;
    char* Al  = lds + 16384;
    char* Bch = lds + 32768;
    char* Bcl = lds + 40960;
    char* Bsh = lds + 49152;
    char* Bsl = lds + 57344;
    const int tid = threadIdx.x, wv = tid >> 6, ln = tid & 63;
    const int wr = wv >> 1, wc = wv & 1, lm = ln & 15, lk = ln >> 4;
    f32x4 ac_h[4][2] = {}, ac_l[4][2] = {}, as_h[4][2] = {}, as_l[4][2] = {};
    const _Float16* Pb = P + (size_t)z * 1024 * 2048 + (size_t)m0 * 2048;
    const size_t vb = (size_t)z * 512 * 1024 + (size_t)n0 * 1024;

    for (int k0 = 0; k0 < 1024; k0 += 64) {
        __syncthreads();
        stageT<128>(Ah, Pb + k0, 2048);
        stageT<128>(Al, Pb + 1024 + k0, 2048);
        stageT<64>(Bch, vch + vb + k0, 1024);
        stageT<64>(Bcl, vcl + vb + k0, 1024);
        stageT<64>(Bsh, vsh + vb + k0, 1024);
        stageT<64>(Bsl, vsl + vb + k0, 1024);
        __syncthreads();
#pragma unroll
        for (int ks = 0; ks < 2; ++ks) {
            half8 bc1[2], bc2[2], bs1[2], bs2[2];
#pragma unroll
            for (int j = 0; j < 2; ++j) {
                const int bn = wc * 32 + j * 16 + lm;
                bc1[j] = fragld(Bch, bn, ks * 4 + lk);
                bc2[j] = fragld(Bcl, bn, ks * 4 + lk);
                bs1[j] = fragld(Bsh, bn, ks * 4 + lk);
                bs2[j] = fragld(Bsl, bn, ks * 4 + lk);
            }
#pragma unroll
            for (int i = 0; i < 4; ++i) {
                const int am = wr * 64 + i * 16 + lm;
                half8 ah = fragld(Ah, am, ks * 4 + lk);
                half8 al = fragld(Al, am, ks * 4 + lk);
#pragma unroll
                for (int j = 0; j < 2; ++j) {
                    ac_h[i][j] = MFMA16(ah, bc1[j], ac_h[i][j]);
                    ac_l[i][j] = MFMA16(ah, bc2[j], ac_l[i][j]);
                    ac_l[i][j] = MFMA16(al, bc1[j], ac_l[i][j]);
                    as_h[i][j] = MFMA16(ah, bs1[j], as_h[i][j]);
                    as_l[i][j] = MFMA16(ah, bs2[j], as_l[i][j]);
                    as_l[i][j] = MFMA16(al, bs1[j], as_l[i][j]);
                }
            }
        }
    }
    const float LS = 1.0f / 4096.0f;
    const int b = z / hcnt, hcl = z % hcnt;
    const int hg = h0 + hcl;
#pragma unroll
    for (int i = 0; i < 4; ++i)
#pragma unroll
        for (int j = 0; j < 2; ++j)
#pragma unroll
            for (int r = 0; r < 4; ++r) {
                const int t = m0 + wr * 64 + i * 16 + lk * 4 + r;
                const int d = n0 + wc * 32 + j * 16 + lm;
                float zc = ac_h[i][j][r] + ac_l[i][j][r] * LS;
                float zs = as_h[i][j][r] + as_l[i][j][r] * LS;
                float inv = 1.0f / sqrtf(fmaxf(zc * zc + zs * zs, 1e-36f));
                float c = zc * inv, s = zs * inv;
                _Float16 chh, chl, shh, shl;
                split2(c, chh, chl); split2(s, shh, shl);
                const size_t off = ((size_t)(b * 1024 + t)) * 4096 + (size_t)hg * 512 + d;
                rch[off] = chh; rcl[off] = chl; rsh[off] = shh; rsl[off] = shl;
            }
}

// ---------------------------------------------------------------------------
// final: z = rz @ wo + bo; out = atan2(zi,zr)/pi. A planes [2048][4096],
// B = woT [512][4096]. Block 64x64, 4 waves (2x2), wave tile 32x32, K=4096.
// ---------------------------------------------------------------------------
__global__ __launch_bounds__(256, 2) void final_mfma(
    const _Float16* __restrict__ rch, const _Float16* __restrict__ rcl,
    const _Float16* __restrict__ rsh, const _Float16* __restrict__ rsl,
    const _Float16* __restrict__ woh, const _Float16* __restrict__ wol,
    const float* __restrict__ bo, float* __restrict__ out)
{
    const int m0 = blockIdx.x * 64, n0 = blockIdx.y * 64;
    __shared__ char lds[49152];
    char* Ach = lds;
    char* Acl = lds + 8192;
    char* Ash = lds + 16384;
    char* Asl = lds + 24576;
    char* Bh  = lds + 32768;
    char* Bl  = lds + 40960;
    const int tid = threadIdx.x, wv = tid >> 6, ln = tid & 63;
    const int wr = wv >> 1, wc = wv & 1, lm = ln & 15, lk = ln >> 4;
    f32x4 rr_h[2][2] = {}, rr_l[2][2] = {}, ri_h[2][2] = {}, ri_l[2][2] = {};

    for (int k0 = 0; k0 < 4096; k0 += 64) {
        __syncthreads();
        stageT<64>(Ach, rch + (size_t)m0 * 4096 + k0, 4096);
        stageT<64>(Acl, rcl + (size_t)m0 * 4096 + k0, 4096);
        stageT<64>(Ash, rsh + (size_t)m0 * 4096 + k0, 4096);
        stageT<64>(Asl, rsl + (size_t)m0 * 4096 + k0, 4096);
        stageT<64>(Bh, woh + (size_t)n0 * 4096 + k0, 4096);
        stageT<64>(Bl, wol + (size_t)n0 * 4096 + k0, 4096);
        __syncthreads();
#pragma unroll
        for (int ks = 0; ks < 2; ++ks) {
            half8 bhf[2], blf[2];
#pragma unroll
            for (int j = 0; j < 2; ++j) {
                bhf[j] = fragld(Bh, wc * 32 + j * 16 + lm, ks * 4 + lk);
                blf[j] = fragld(Bl, wc * 32 + j * 16 + lm, ks * 4 + lk);
            }
#pragma unroll
            for (int i = 0; i < 2; ++i) {
                const int am = wr * 32 + i * 16 + lm;
                half8 a1 = fragld(Ach, am, ks * 4 + lk);
                half8 a2 = fragld(Acl, am, ks * 4 + lk);
                half8 a3 = fragld(Ash, am, ks * 4 + lk);
                half8 a4 = fragld(Asl, am, ks * 4 + lk);
#pragma unroll
                for (int j = 0; j < 2; ++j) {
                    rr_h[i][j] = MFMA16(a1, bhf[j], rr_h[i][j]);
                    rr_l[i][j] = MFMA16(a1, blf[j], rr_l[i][j]);
                    rr_l[i][j] = MFMA16(a2, bhf[j], rr_l[i][j]);
                    ri_h[i][j] = MFMA16(a3, bhf[j], ri_h[i][j]);
                    ri_l[i][j] = MFMA16(a3, blf[j], ri_l[i][j]);
                    ri_l[i][j] = MFMA16(a4, bhf[j], ri_l[i][j]);
                }
            }
        }
    }
    const float LS = 1.0f / 4096.0f;
#pragma unroll
    for (int j = 0; j < 2; ++j) {
        const int nloc = wc * 32 + j * 16 + lm;
        const float bval = bo[n0 + nloc];
#pragma unroll
        for (int i = 0; i < 2; ++i)
#pragma unroll
            for (int r = 0; r < 4; ++r) {
                const int mloc = wr * 32 + i * 16 + lk * 4 + r;
                float zr = rr_h[i][j][r] + rr_l[i][j][r] * LS + bval;
                float zi = ri_h[i][j][r] + ri_l[i][j][r] * LS;
                out[(size_t)(m0 + mloc) * 512 + n0 + nloc] = atan2f(zi, zr) / PI_F;
            }
    }
}

// ---------------------------------------------------------------------------
extern "C" void kernel_launch(void* const* d_in, const int* in_sizes, int n_in,
                              void* d_out, int out_size, void* d_ws, size_t ws_size,
                              hipStream_t stream)
{
    (void)in_sizes; (void)n_in; (void)out_size;
    const float* query    = (const float*)d_in[0];
    const float* keyvalue = (const float*)d_in[1];
    const float* wq = (const float*)d_in[2];
    const float* bq = (const float*)d_in[3];
    const float* wk = (const float*)d_in[4];
    const float* bk = (const float*)d_in[5];
    const float* wv = (const float*)d_in[6];
    const float* bv = (const float*)d_in[7];
    const float* wo = (const float*)d_in[8];
    const float* bo = (const float*)d_in[9];
    float* out = (float*)d_out;

    // head-chunking: full layout needs ~368MB, chunked (2 heads) ~158MB.
    const int hcnt = (ws_size >= (size_t)380 * 1024 * 1024) ? 8 : 2;
    const int Z = 2 * hcnt;

    char* p = (char*)d_ws;
    auto alloc = [&](size_t bytes) {
        char* r = p;
        p += (bytes + 255) & ~(size_t)255;
        return r;
    };
    const size_t PLX = (size_t)2048 * 512;       // encode plane elems
    _Float16* xq[4]; for (int i = 0; i < 4; ++i) xq[i] = (_Float16*)alloc(PLX * 2);
    _Float16* xk[4]; for (int i = 0; i < 4; ++i) xk[i] = (_Float16*)alloc(PLX * 2);
    _Float16* woT[2]; for (int i = 0; i < 2; ++i) woT[i] = (_Float16*)alloc((size_t)512 * 4096 * 2);
    _Float16* rcs[4]; for (int i = 0; i < 4; ++i) rcs[i] = (_Float16*)alloc((size_t)2048 * 4096 * 2);
    const size_t WTE = (size_t)hcnt * 512 * 512;
    _Float16* wqT[2]; for (int i = 0; i < 2; ++i) wqT[i] = (_Float16*)alloc(WTE * 2);
    _Float16* wkT[2]; for (int i = 0; i < 2; ++i) wkT[i] = (_Float16*)alloc(WTE * 2);
    _Float16* wvT[2]; for (int i = 0; i < 2; ++i) wvT[i] = (_Float16*)alloc(WTE * 2);
    const size_t QZE = (size_t)Z * 1024 * 1024;
    _Float16* qz[2]; for (int i = 0; i < 2; ++i) qz[i] = (_Float16*)alloc(QZE * 2);
    _Float16* kz[2]; for (int i = 0; i < 2; ++i) kz[i] = (_Float16*)alloc(QZE * 2);
    float* S = (float*)alloc(QZE * 4);
    const size_t VTE = (size_t)Z * 512 * 1024;
    _Float16* vT[4]; for (int i = 0; i < 4; ++i) vT[i] = (_Float16*)alloc(VTE * 2);

    dim3 blk(256);

    encode_phasor<<<1024, blk, 0, stream>>>(query, xq[0], xq[1], xq[2], xq[3]);
    encode_phasor<<<1024, blk, 0, stream>>>(keyvalue, xk[0], xk[1], xk[2], xk[3]);
    tsplit64<<<dim3(64, 8, 1), blk, 0, stream>>>(wo, woT[0], woT[1], 4096, 512);

    for (int c = 0; c < 8 / hcnt; ++c) {
        const int h0 = c * hcnt;
        const float* wqc = wq + (size_t)h0 * 512 * 512;
        const float* wkc = wk + (size_t)h0 * 512 * 512;
        const float* wvc = wv + (size_t)h0 * 512 * 512;
        tsplit64<<<dim3(8, 8, hcnt), blk, 0, stream>>>(wqc, wqT[0], wqT[1], 512, 512);
        tsplit64<<<dim3(8, 8, hcnt), blk, 0, stream>>>(wkc, wkT[0], wkT[1], 512, 512);
        tsplit64<<<dim3(8, 8, hcnt), blk, 0, stream>>>(wvc, wvT[0], wvT[1], 512, 512);

        proj_mfma<false><<<dim3(16, hcnt * 8), blk, 0, stream>>>(
            xq[0], xq[1], xq[2], xq[3], wqT[0], wqT[1], bq,
            qz[0], qz[1], nullptr, nullptr, nullptr, nullptr, h0, hcnt);
        proj_mfma<false><<<dim3(16, hcnt * 8), blk, 0, stream>>>(
            xk[0], xk[1], xk[2], xk[3], wkT[0], wkT[1], bk,
            kz[0], kz[1], nullptr, nullptr, nullptr, nullptr, h0, hcnt);
        proj_mfma<true><<<dim3(16, hcnt * 8), blk, 0, stream>>>(
            xk[0], xk[1], xk[2], xk[3], wvT[0], wvT[1], bv,
            nullptr, nullptr, vT[0], vT[1], vT[2], vT[3], h0, hcnt);

        scores_mfma<<<dim3(8, 8, Z), blk, 0, stream>>>(qz[0], qz[1], kz[0], kz[1], S);
        softmax_split<<<dim3(Z * 1024), blk, 0, stream>>>(S);
        pv_mfma<<<dim3(8, 8, Z), blk, 0, stream>>>(
            (const _Float16*)S, vT[0], vT[1], vT[2], vT[3],
            rcs[0], rcs[1], rcs[2], rcs[3], h0, hcnt);
    }

    final_mfma<<<dim3(32, 8), blk, 0, stream>>>(
        rcs[0], rcs[1], rcs[2], rcs[3], woT[0], woT[1], bo, out);
}

// Round 3
// 608.561 us; speedup vs baseline: 3.6666x; 1.2461x over previous
//
#include <hip/hip_runtime.h>
#include <math.h>

// Phasor attention via split-fp16 MFMA (fp16x2 error-free splitting, ~fp32 accuracy).
// B=2, T=1024, D=512, H=8.
// Round 3: 2-phase double-buffered LDS prefetch (one __syncthreads per K-step),
// hi/lo-interleaved 128B LDS rows with XOR swizzle (BK=32), setprio around MFMA,
// occupancy-tuned tiles (scores/pv 2 blk/CU, proj/final 3 blk/CU).

#define PI_F 3.14159274101257324f

typedef __attribute__((ext_vector_type(8))) _Float16 half8;
typedef __attribute__((ext_vector_type(4))) _Float16 half4;
typedef __attribute__((ext_vector_type(2))) _Float16 half2v;
typedef __attribute__((ext_vector_type(4))) float f32x4;
typedef unsigned int u32;

#define MFMA16(a, b, c) __builtin_amdgcn_mfma_f32_16x16x32_f16((a), (b), (c), 0, 0, 0)

__device__ __forceinline__ void gll16(const void* g, void* l) {
    __builtin_amdgcn_global_load_lds(
        (const __attribute__((address_space(1))) u32*)g,
        (__attribute__((address_space(3))) u32*)l, 16, 0, 0);
}

// LDS row format: 128B = 8x16B slots; logical slots 0-3 = hi plane (32 fp16),
// 4-7 = lo plane; stored slot = logical ^ (row&7).  BK = 32.
// MKSRC precomputes per-unit global srcs + LDS dest offsets (NT threads, U units,
// R rows where U = R*8/NT).
#define MKSRC(U, NT, gh, gl, stride, sp, dp, dbase)                         \
    _Pragma("unroll") for (int u_ = 0; u_ < (U); ++u_) {                    \
        const int idx_ = u_ * (NT) + tid;                                   \
        const int row_ = idx_ >> 3, ss_ = idx_ & 7;                         \
        const int sl_ = ss_ ^ (row_ & 7);                                   \
        sp[u_] = ((sl_ < 4) ? (gh) : (gl)) + (size_t)row_ * (stride)        \
                 + (sl_ & 3) * 8;                                           \
        dp[u_] = (dbase) + idx_ * 16;                                       \
    }
#define STAGE(U, sp, dp, bufoff, kk)                                        \
    _Pragma("unroll") for (int u_ = 0; u_ < (U); ++u_)                      \
        gll16(sp[u_] + (kk), lds + (bufoff) + dp[u_]);

// Fragment read: 8 fp16 (k-octet oct in [0,4), hilo 0/1) with XOR de-swizzle.
__device__ __forceinline__ half8 fragP(const char* ldsp, int row, int oct, int hilo) {
    const int sl = (oct + hilo * 4) ^ (row & 7);
    return *(const half8*)(ldsp + row * 128 + (sl << 4));
}

__device__ __forceinline__ void split2(float x, _Float16& h, _Float16& l) {
    _Float16 hh = (_Float16)x;
    h = hh;
    l = (_Float16)((x - (float)hh) * 4096.0f);
}

// ---------------------------------------------------------------------------
// encode: x [2048*512] f32 -> phasor planes cos/sin hi/lo [2048][512] fp16.
// ---------------------------------------------------------------------------
__global__ __launch_bounds__(256) void encode_phasor(
    const float* __restrict__ x,
    _Float16* __restrict__ ch, _Float16* __restrict__ cl,
    _Float16* __restrict__ sh, _Float16* __restrict__ sl)
{
    const int idx = blockIdx.x * 256 + threadIdx.x;
    float4 v = ((const float4*)x)[idx];
    float cc[4], ss[4];
    sincosf(PI_F * v.x, &ss[0], &cc[0]);
    sincosf(PI_F * v.y, &ss[1], &cc[1]);
    sincosf(PI_F * v.z, &ss[2], &cc[2]);
    sincosf(PI_F * v.w, &ss[3], &cc[3]);
    half4 chv, clv, shv, slv;
#pragma unroll
    for (int q = 0; q < 4; ++q) {
        _Float16 a, b;
        split2(cc[q], a, b); chv[q] = a; clv[q] = b;
        split2(ss[q], a, b); shv[q] = a; slv[q] = b;
    }
    ((half4*)ch)[idx] = chv;
    ((half4*)cl)[idx] = clv;
    ((half4*)sh)[idx] = shv;
    ((half4*)sl)[idx] = slv;
}

// ---------------------------------------------------------------------------
// tsplit64: w [h][K][N] f32 -> transposed split planes th/tl [h][N][K] fp16.
// ---------------------------------------------------------------------------
__global__ __launch_bounds__(256) void tsplit64(
    const float* __restrict__ w, _Float16* __restrict__ th, _Float16* __restrict__ tl,
    int K, int N)
{
    const int kt = blockIdx.x, ntile = blockIdx.y, h = blockIdx.z;
    const int k0 = kt * 64, n0 = ntile * 64;
    __shared__ float T[64][65];
    const int tid = threadIdx.x;
    const float* wb = w + (size_t)h * K * N;
    {
        const int r = tid >> 4, c4 = (tid & 15) * 4;
#pragma unroll
        for (int rr = 0; rr < 64; rr += 16) {
            float4 v = *(const float4*)&wb[(size_t)(k0 + rr + r) * N + n0 + c4];
            T[rr + r][c4 + 0] = v.x; T[rr + r][c4 + 1] = v.y;
            T[rr + r][c4 + 2] = v.z; T[rr + r][c4 + 3] = v.w;
        }
    }
    __syncthreads();
    {
        const int n = tid >> 2, kq = (tid & 3) * 16;
        half8 hv[2], lv[2];
#pragma unroll
        for (int q = 0; q < 16; ++q) {
            float f = T[kq + q][n];
            _Float16 hh, ll; split2(f, hh, ll);
            hv[q >> 3][q & 7] = hh; lv[q >> 3][q & 7] = ll;
        }
        _Float16* oh = th + ((size_t)h * N + n0 + n) * K + k0 + kq;
        _Float16* ol = tl + ((size_t)h * N + n0 + n) * K + k0 + kq;
        *(half8*)oh = hv[0]; *(half8*)(oh + 8) = hv[1];
        *(half8*)ol = lv[0]; *(half8*)(ol + 8) = lv[1];
    }
}

// ---------------------------------------------------------------------------
// proj: y = phasor(x) @ w + bias -> normalize -> split planes.
// Block 64x64, BK=32, dbuf 48KB -> 3 blocks/CU. Waves 2x2, wave-tile 32x32.
// VT=0: qz interleaved (c,s) planes [Z][1024][1024] hi/lo.
// VT=1: vT planes [Z][512 d][1024 t] via chunked LDS transpose epilogue.
// ---------------------------------------------------------------------------
template<bool VT>
__global__ __launch_bounds__(256, 3) void proj_mfma(
    const _Float16* __restrict__ xch, const _Float16* __restrict__ xcl,
    const _Float16* __restrict__ xsh, const _Float16* __restrict__ xsl,
    const _Float16* __restrict__ wth, const _Float16* __restrict__ wtl,
    const float* __restrict__ bias,
    _Float16* __restrict__ o0h, _Float16* __restrict__ o0l,
    _Float16* __restrict__ vch, _Float16* __restrict__ vcl,
    _Float16* __restrict__ vsh, _Float16* __restrict__ vsl,
    int h0, int hcnt)
{
    const int m0 = blockIdx.x * 64;
    const int hc = blockIdx.y >> 3;
    const int n0 = (blockIdx.y & 7) * 64;
    __shared__ char lds[49152];   // buf: [Xc 8K][Xs 8K][W 8K] x2
    const int tid = threadIdx.x, wv = tid >> 6, ln = tid & 63;
    const int wr = wv >> 1, wc = wv & 1, lm = ln & 15, oct = ln >> 4;

    const _Float16* sp_xc[2]; int dp_xc[2];
    const _Float16* sp_xs[2]; int dp_xs[2];
    const _Float16* sp_w[2];  int dp_w[2];
    MKSRC(2, 256, xch + (size_t)m0 * 512, xcl + (size_t)m0 * 512, 512, sp_xc, dp_xc, 0);
    MKSRC(2, 256, xsh + (size_t)m0 * 512, xsl + (size_t)m0 * 512, 512, sp_xs, dp_xs, 8192);
    const _Float16* wbh = wth + ((size_t)hc * 512 + n0) * 512;
    const _Float16* wbl = wtl + ((size_t)hc * 512 + n0) * 512;
    MKSRC(2, 256, wbh, wbl, 512, sp_w, dp_w, 16384);

    f32x4 ach[2][2] = {}, acl[2][2] = {}, ash[2][2] = {}, asl[2][2] = {};

    STAGE(2, sp_xc, dp_xc, 0, 0);
    STAGE(2, sp_xs, dp_xs, 0, 0);
    STAGE(2, sp_w,  dp_w,  0, 0);
    int off = 0;
    for (int s = 0; s < 16; ++s) {
        __syncthreads();
        const int nxt = off ^ 24576;
        if (s + 1 < 16) {
            const int kk = (s + 1) * 32;
            STAGE(2, sp_xc, dp_xc, nxt, kk);
            STAGE(2, sp_xs, dp_xs, nxt, kk);
            STAGE(2, sp_w,  dp_w,  nxt, kk);
        }
        const char* Xc = lds + off;
        const char* Xs = lds + off + 8192;
        const char* W  = lds + off + 16384;
        __builtin_amdgcn_s_setprio(1);
        half8 wh[2], wl[2];
#pragma unroll
        for (int j = 0; j < 2; ++j) {
            wh[j] = fragP(W, wc * 32 + j * 16 + lm, oct, 0);
            wl[j] = fragP(W, wc * 32 + j * 16 + lm, oct, 1);
        }
#pragma unroll
        for (int i = 0; i < 2; ++i) {
            const int ar = wr * 32 + i * 16 + lm;
            half8 c1 = fragP(Xc, ar, oct, 0);
            half8 c2 = fragP(Xc, ar, oct, 1);
            half8 s1 = fragP(Xs, ar, oct, 0);
            half8 s2 = fragP(Xs, ar, oct, 1);
#pragma unroll
            for (int j = 0; j < 2; ++j) {
                ach[i][j] = MFMA16(c1, wh[j], ach[i][j]);
                acl[i][j] = MFMA16(c1, wl[j], acl[i][j]);
                acl[i][j] = MFMA16(c2, wh[j], acl[i][j]);
                ash[i][j] = MFMA16(s1, wh[j], ash[i][j]);
                asl[i][j] = MFMA16(s1, wl[j], asl[i][j]);
                asl[i][j] = MFMA16(s2, wh[j], asl[i][j]);
            }
        }
        __builtin_amdgcn_s_setprio(0);
        off = nxt;
    }

    const float LS = 1.0f / 4096.0f;
    const int b = m0 >> 10, tbase = m0 & 1023;
    const size_t zz = (size_t)(b * hcnt + hc);
    if constexpr (!VT) {
#pragma unroll
        for (int j = 0; j < 2; ++j) {
            const int nloc = wc * 32 + j * 16 + lm;
            const float bval = bias[(size_t)(h0 + hc) * 512 + n0 + nloc];
#pragma unroll
            for (int i = 0; i < 2; ++i)
#pragma unroll
                for (int r = 0; r < 4; ++r) {
                    const int mloc = wr * 32 + i * 16 + oct * 4 + r;
                    float yc = ach[i][j][r] + acl[i][j][r] * LS + bval;
                    float ys = ash[i][j][r] + asl[i][j][r] * LS;
                    float inv = 1.0f / sqrtf(fmaxf(yc * yc + ys * ys, 1e-36f));
                    float c = yc * inv, sn = ys * inv;
                    _Float16 chh, chl, shh, shl;
                    split2(c, chh, chl); split2(sn, shh, shl);
                    const size_t offo = (zz * 1024 + tbase + mloc) * 1024 + 2 * (n0 + nloc);
                    half2v hv, lv;
                    hv[0] = chh; hv[1] = shh; lv[0] = chl; lv[1] = shl;
                    *(half2v*)(o0h + offo) = hv;
                    *(half2v*)(o0l + offo) = lv;
                }
        }
    } else {
        // chunked LDS transpose: 2 chunks of 32 d; T planes [32][68] fp16 x4
#pragma unroll
        for (int q = 0; q < 2; ++q) {
            __syncthreads();
            if (wc == q) {
#pragma unroll
                for (int j = 0; j < 2; ++j) {
                    const int nloc = wc * 32 + j * 16 + lm;
                    const int dch = j * 16 + lm;
                    const float bval = bias[(size_t)(h0 + hc) * 512 + n0 + nloc];
#pragma unroll
                    for (int i = 0; i < 2; ++i)
#pragma unroll
                        for (int r = 0; r < 4; ++r) {
                            const int tloc = wr * 32 + i * 16 + oct * 4 + r;
                            float yc = ach[i][j][r] + acl[i][j][r] * LS + bval;
                            float ys = ash[i][j][r] + asl[i][j][r] * LS;
                            float inv = 1.0f / sqrtf(fmaxf(yc * yc + ys * ys, 1e-36f));
                            float c = yc * inv, sn = ys * inv;
                            _Float16 chh, chl, shh, shl;
                            split2(c, chh, chl); split2(sn, shh, shl);
                            ((_Float16*)(lds +     0))[dch * 68 + tloc] = chh;
                            ((_Float16*)(lds +  4352))[dch * 68 + tloc] = chl;
                            ((_Float16*)(lds +  8704))[dch * 68 + tloc] = shh;
                            ((_Float16*)(lds + 13056))[dch * 68 + tloc] = shl;
                        }
                }
            }
            __syncthreads();
            {
                const int p = tid >> 6, rem = tid & 63;
                const int dch = rem >> 1, seg = rem & 1;
                const _Float16* src = (const _Float16*)(lds + p * 4352) + dch * 68 + seg * 32;
                _Float16* outp = (p == 0) ? vch : (p == 1) ? vcl : (p == 2) ? vsh : vsl;
                _Float16* dst = outp + (zz * 512 + n0 + q * 32 + dch) * 1024 + tbase + seg * 32;
#pragma unroll
                for (int t = 0; t < 4; ++t)
                    *(half8*)(dst + t * 8) = *(const half8*)(src + t * 8);
            }
        }
    }
}

// ---------------------------------------------------------------------------
// scores: S[z][t][T] = (qz . kz)/512, K=1024 (c,s interleaved).
// Block 128x128, BK=32, dbuf 64KB -> 2 blocks/CU. Waves 2x2, wave-tile 64x64.
// ---------------------------------------------------------------------------
__global__ __launch_bounds__(256, 2) void scores_mfma(
    const _Float16* __restrict__ qzh, const _Float16* __restrict__ qzl,
    const _Float16* __restrict__ kzh, const _Float16* __restrict__ kzl,
    float* __restrict__ S)
{
    const int m0 = blockIdx.x * 128, n0 = blockIdx.y * 128, z = blockIdx.z;
    __shared__ char lds[65536];  // buf: [A 16K][B 16K] x2
    const size_t zb = (size_t)z << 20;
    const int tid = threadIdx.x, wv = tid >> 6, ln = tid & 63;
    const int wr = wv >> 1, wc = wv & 1, lm = ln & 15, oct = ln >> 4;

    const _Float16* sp_a[4]; int dp_a[4];
    const _Float16* sp_b[4]; int dp_b[4];
    MKSRC(4, 256, qzh + zb + (size_t)m0 * 1024, qzl + zb + (size_t)m0 * 1024, 1024, sp_a, dp_a, 0);
    MKSRC(4, 256, kzh + zb + (size_t)n0 * 1024, kzl + zb + (size_t)n0 * 1024, 1024, sp_b, dp_b, 16384);

    f32x4 acch[4][4] = {}, accl[4][4] = {};

    STAGE(4, sp_a, dp_a, 0, 0);
    STAGE(4, sp_b, dp_b, 0, 0);
    int off = 0;
    for (int s = 0; s < 32; ++s) {
        __syncthreads();
        const int nxt = off ^ 32768;
        if (s + 1 < 32) {
            const int kk = (s + 1) * 32;
            STAGE(4, sp_a, dp_a, nxt, kk);
            STAGE(4, sp_b, dp_b, nxt, kk);
        }
        const char* A = lds + off;
        const char* Bb = lds + off + 16384;
        __builtin_amdgcn_s_setprio(1);
        half8 bh[4], bl[4];
#pragma unroll
        for (int j = 0; j < 4; ++j) {
            bh[j] = fragP(Bb, wc * 64 + j * 16 + lm, oct, 0);
            bl[j] = fragP(Bb, wc * 64 + j * 16 + lm, oct, 1);
        }
#pragma unroll
        for (int i = 0; i < 4; ++i) {
            half8 ah = fragP(A, wr * 64 + i * 16 + lm, oct, 0);
            half8 al = fragP(A, wr * 64 + i * 16 + lm, oct, 1);
#pragma unroll
            for (int j = 0; j < 4; ++j) {
                acch[i][j] = MFMA16(ah, bh[j], acch[i][j]);
                accl[i][j] = MFMA16(ah, bl[j], accl[i][j]);
                accl[i][j] = MFMA16(al, bh[j], accl[i][j]);
            }
        }
        __builtin_amdgcn_s_setprio(0);
        off = nxt;
    }
    const float LS = 1.0f / 4096.0f, SC = 1.0f / 512.0f;
#pragma unroll
    for (int i = 0; i < 4; ++i)
#pragma unroll
        for (int j = 0; j < 4; ++j)
#pragma unroll
            for (int r = 0; r < 4; ++r) {
                const int row = m0 + wr * 64 + i * 16 + oct * 4 + r;
                const int col = n0 + wc * 64 + j * 16 + lm;
                S[zb + (size_t)row * 1024 + col] =
                    (acch[i][j][r] + accl[i][j][r] * LS) * SC;
            }
}

// ---------------------------------------------------------------------------
// softmax rows of 1024 (max-subtracted); write P fp16 hi/lo split in place.
// ---------------------------------------------------------------------------
__global__ __launch_bounds__(256) void softmax_split(float* __restrict__ S)
{
    const size_t row = blockIdx.x;
    float* p = S + row * 1024;
    const int tid = threadIdx.x;
    float4 v = ((const float4*)p)[tid];
    float m = fmaxf(fmaxf(v.x, v.y), fmaxf(v.z, v.w));
#pragma unroll
    for (int off = 32; off >= 1; off >>= 1)
        m = fmaxf(m, __shfl_xor(m, off));
    __shared__ float redm[4], reds[4];
    const int wid = tid >> 6, lane = tid & 63;
    if (lane == 0) redm[wid] = m;
    __syncthreads();
    m = fmaxf(fmaxf(redm[0], redm[1]), fmaxf(redm[2], redm[3]));
    float4 e;
    e.x = expf(v.x - m); e.y = expf(v.y - m);
    e.z = expf(v.z - m); e.w = expf(v.w - m);
    float s = (e.x + e.y) + (e.z + e.w);
#pragma unroll
    for (int off = 32; off >= 1; off >>= 1)
        s += __shfl_xor(s, off);
    if (lane == 0) reds[wid] = s;
    __syncthreads();
    s = (reds[0] + reds[1]) + (reds[2] + reds[3]);
    e.x /= s; e.y /= s; e.z /= s; e.w /= s;
    __syncthreads();
    _Float16* ph = (_Float16*)p;
    half4 hv, lv;
    _Float16 a, b;
    split2(e.x, a, b); hv[0] = a; lv[0] = b;
    split2(e.y, a, b); hv[1] = a; lv[1] = b;
    split2(e.z, a, b); hv[2] = a; lv[2] = b;
    split2(e.w, a, b); hv[3] = a; lv[3] = b;
    *(half4*)(ph + tid * 4) = hv;
    *(half4*)(ph + 1024 + tid * 4) = lv;
}

// ---------------------------------------------------------------------------
// pv: out[z][t][d] = sum_T P[t][T] * vz[T][d], normalize, split, write rcs.
// Block 128x64, BK=32, dbuf 64KB -> 2 blocks/CU. Waves 2x2, wave-tile 64x32.
// ---------------------------------------------------------------------------
__global__ __launch_bounds__(256, 2) void pv_mfma(
    const _Float16* __restrict__ P,
    const _Float16* __restrict__ vch, const _Float16* __restrict__ vcl,
    const _Float16* __restrict__ vsh, const _Float16* __restrict__ vsl,
    _Float16* __restrict__ rch, _Float16* __restrict__ rcl,
    _Float16* __restrict__ rsh, _Float16* __restrict__ rsl,
    int h0, int hcnt)
{
    const int m0 = blockIdx.x * 128, n0 = blockIdx.y * 64, z = blockIdx.z;
    __shared__ char lds[65536];  // buf: [P 16K][Vc 8K][Vs 8K] x2
    const int tid = threadIdx.x, wv = tid >> 6, ln = tid & 63;
    const int wr = wv >> 1, wc = wv & 1, lm = ln & 15, oct = ln >> 4;

    const _Float16* Pb = P + (size_t)z * 1024 * 2048 + (size_t)m0 * 2048;
    const size_t vb = (size_t)z * 512 * 1024 + (size_t)n0 * 1024;
    const _Float16* sp_p[4];  int dp_p[4];
    const _Float16* sp_vc[2]; int dp_vc[2];
    const _Float16* sp_vs[2]; int dp_vs[2];
    MKSRC(4, 256, Pb, Pb + 1024, 2048, sp_p, dp_p, 0);
    MKSRC(2, 256, vch + vb, vcl + vb, 1024, sp_vc, dp_vc, 16384);
    MKSRC(2, 256, vsh + vb, vsl + vb, 1024, sp_vs, dp_vs, 24576);

    f32x4 ac_h[4][2] = {}, ac_l[4][2] = {}, as_h[4][2] = {}, as_l[4][2] = {};

    STAGE(4, sp_p,  dp_p,  0, 0);
    STAGE(2, sp_vc, dp_vc, 0, 0);
    STAGE(2, sp_vs, dp_vs, 0, 0);
    int off = 0;
    for (int s = 0; s < 32; ++s) {
        __syncthreads();
        const int nxt = off ^ 32768;
        if (s + 1 < 32) {
            const int kk = (s + 1) * 32;
            STAGE(4, sp_p,  dp_p,  nxt, kk);
            STAGE(2, sp_vc, dp_vc, nxt, kk);
            STAGE(2, sp_vs, dp_vs, nxt, kk);
        }
        const char* A  = lds + off;
        const char* Vc = lds + off + 16384;
        const char* Vs = lds + off + 24576;
        __builtin_amdgcn_s_setprio(1);
        half8 bc1[2], bc2[2], bs1[2], bs2[2];
#pragma unroll
        for (int j = 0; j < 2; ++j) {
            const int bn = wc * 32 + j * 16 + lm;
            bc1[j] = fragP(Vc, bn, oct, 0);
            bc2[j] = fragP(Vc, bn, oct, 1);
            bs1[j] = fragP(Vs, bn, oct, 0);
            bs2[j] = fragP(Vs, bn, oct, 1);
        }
#pragma unroll
        for (int i = 0; i < 4; ++i) {
            const int am = wr * 64 + i * 16 + lm;
            half8 ah = fragP(A, am, oct, 0);
            half8 al = fragP(A, am, oct, 1);
#pragma unroll
            for (int j = 0; j < 2; ++j) {
                ac_h[i][j] = MFMA16(ah, bc1[j], ac_h[i][j]);
                ac_l[i][j] = MFMA16(ah, bc2[j], ac_l[i][j]);
                ac_l[i][j] = MFMA16(al, bc1[j], ac_l[i][j]);
                as_h[i][j] = MFMA16(ah, bs1[j], as_h[i][j]);
                as_l[i][j] = MFMA16(ah, bs2[j], as_l[i][j]);
                as_l[i][j] = MFMA16(al, bs1[j], as_l[i][j]);
            }
        }
        __builtin_amdgcn_s_setprio(0);
        off = nxt;
    }
    const float LS = 1.0f / 4096.0f;
    const int b = z / hcnt, hg = h0 + z % hcnt;
#pragma unroll
    for (int i = 0; i < 4; ++i)
#pragma unroll
        for (int j = 0; j < 2; ++j)
#pragma unroll
            for (int r = 0; r < 4; ++r) {
                const int t = m0 + wr * 64 + i * 16 + oct * 4 + r;
                const int d = n0 + wc * 32 + j * 16 + lm;
                float zc = ac_h[i][j][r] + ac_l[i][j][r] * LS;
                float zs = as_h[i][j][r] + as_l[i][j][r] * LS;
                float inv = 1.0f / sqrtf(fmaxf(zc * zc + zs * zs, 1e-36f));
                float c = zc * inv, sn = zs * inv;
                _Float16 chh, chl, shh, shl;
                split2(c, chh, chl); split2(sn, shh, shl);
                const size_t offo = ((size_t)(b * 1024 + t)) * 4096 + (size_t)hg * 512 + d;
                rch[offo] = chh; rcl[offo] = chl; rsh[offo] = shh; rsl[offo] = shl;
            }
}

// ---------------------------------------------------------------------------
// final: z = rz @ wo + bo; out = atan2(zi,zr)/pi. K=4096.
// Block 64x64, BK=32, dbuf 48KB -> 3 blocks/CU. Waves 2x2, wave-tile 32x32.
// ---------------------------------------------------------------------------
__global__ __launch_bounds__(256, 3) void final_mfma(
    const _Float16* __restrict__ rch, const _Float16* __restrict__ rcl,
    const _Float16* __restrict__ rsh, const _Float16* __restrict__ rsl,
    const _Float16* __restrict__ woh, const _Float16* __restrict__ wol,
    const float* __restrict__ bo, float* __restrict__ out)
{
    const int m0 = blockIdx.x * 64, n0 = blockIdx.y * 64;
    __shared__ char lds[49152];  // buf: [Rc 8K][Rs 8K][Wo 8K] x2
    const int tid = threadIdx.x, wv = tid >> 6, ln = tid & 63;
    const int wr = wv >> 1, wc = wv & 1, lm = ln & 15, oct = ln >> 4;

    const _Float16* sp_rc[2]; int dp_rc[2];
    const _Float16* sp_rs[2]; int dp_rs[2];
    const _Float16* sp_w[2];  int dp_w[2];
    MKSRC(2, 256, rch + (size_t)m0 * 4096, rcl + (size_t)m0 * 4096, 4096, sp_rc, dp_rc, 0);
    MKSRC(2, 256, rsh + (size_t)m0 * 4096, rsl + (size_t)m0 * 4096, 4096, sp_rs, dp_rs, 8192);
    MKSRC(2, 256, woh + (size_t)n0 * 4096, wol + (size_t)n0 * 4096, 4096, sp_w, dp_w, 16384);

    f32x4 rr_h[2][2] = {}, rr_l[2][2] = {}, ri_h[2][2] = {}, ri_l[2][2] = {};

    STAGE(2, sp_rc, dp_rc, 0, 0);
    STAGE(2, sp_rs, dp_rs, 0, 0);
    STAGE(2, sp_w,  dp_w,  0, 0);
    int off = 0;
    for (int s = 0; s < 128; ++s) {
        __syncthreads();
        const int nxt = off ^ 24576;
        if (s + 1 < 128) {
            const int kk = (s + 1) * 32;
            STAGE(2, sp_rc, dp_rc, nxt, kk);
            STAGE(2, sp_rs, dp_rs, nxt, kk);
            STAGE(2, sp_w,  dp_w,  nxt, kk);
        }
        const char* Rc = lds + off;
        const char* Rs = lds + off + 8192;
        const char* W  = lds + off + 16384;
        __builtin_amdgcn_s_setprio(1);
        half8 wh[2], wl[2];
#pragma unroll
        for (int j = 0; j < 2; ++j) {
            wh[j] = fragP(W, wc * 32 + j * 16 + lm, oct, 0);
            wl[j] = fragP(W, wc * 32 + j * 16 + lm, oct, 1);
        }
#pragma unroll
        for (int i = 0; i < 2; ++i) {
            const int ar = wr * 32 + i * 16 + lm;
            half8 c1 = fragP(Rc, ar, oct, 0);
            half8 c2 = fragP(Rc, ar, oct, 1);
            half8 s1 = fragP(Rs, ar, oct, 0);
            half8 s2 = fragP(Rs, ar, oct, 1);
#pragma unroll
            for (int j = 0; j < 2; ++j) {
                rr_h[i][j] = MFMA16(c1, wh[j], rr_h[i][j]);
                rr_l[i][j] = MFMA16(c1, wl[j], rr_l[i][j]);
                rr_l[i][j] = MFMA16(c2, wh[j], rr_l[i][j]);
                ri_h[i][j] = MFMA16(s1, wh[j], ri_h[i][j]);
                ri_l[i][j] = MFMA16(s1, wl[j], ri_l[i][j]);
                ri_l[i][j] = MFMA16(s2, wh[j], ri_l[i][j]);
            }
        }
        __builtin_amdgcn_s_setprio(0);
        off = nxt;
    }
    const float LS = 1.0f / 4096.0f;
#pragma unroll
    for (int j = 0; j < 2; ++j) {
        const int nloc = wc * 32 + j * 16 + lm;
        const float bval = bo[n0 + nloc];
#pragma unroll
        for (int i = 0; i < 2; ++i)
#pragma unroll
            for (int r = 0; r < 4; ++r) {
                const int mloc = wr * 32 + i * 16 + oct * 4 + r;
                float zr = rr_h[i][j][r] + rr_l[i][j][r] * LS + bval;
                float zi = ri_h[i][j][r] + ri_l[i][j][r] * LS;
                out[(size_t)(m0 + mloc) * 512 + n0 + nloc] = atan2f(zi, zr) / PI_F;
            }
    }
}

// ---------------------------------------------------------------------------
extern "C" void kernel_launch(void* const* d_in, const int* in_sizes, int n_in,
                              void* d_out, int out_size, void* d_ws, size_t ws_size,
                              hipStream_t stream)
{
    (void)in_sizes; (void)n_in; (void)out_size;
    const float* query    = (const float*)d_in[0];
    const float* keyvalue = (const float*)d_in[1];
    const float* wq = (const float*)d_in[2];
    const float* bq = (const float*)d_in[3];
    const float* wk = (const float*)d_in[4];
    const float* bk = (const float*)d_in[5];
    const float* wv = (const float*)d_in[6];
    const float* bv = (const float*)d_in[7];
    const float* wo = (const float*)d_in[8];
    const float* bo = (const float*)d_in[9];
    float* out = (float*)d_out;

    // memory tiers: hcnt=8 (rcs overlays dead qz/kz) ~304MB; 4 ~228MB; 2 ~158MB.
    int hcnt;
    if (ws_size >= (size_t)320 * 1024 * 1024) hcnt = 8;
    else if (ws_size >= (size_t)240 * 1024 * 1024) hcnt = 4;
    else hcnt = 2;
    const int Z = 2 * hcnt;

    char* p = (char*)d_ws;
    auto alloc = [&](size_t bytes) {
        char* r = p;
        p += (bytes + 255) & ~(size_t)255;
        return r;
    };
    const size_t PLX = (size_t)2048 * 512;
    _Float16* xq[4]; for (int i = 0; i < 4; ++i) xq[i] = (_Float16*)alloc(PLX * 2);
    _Float16* xk[4]; for (int i = 0; i < 4; ++i) xk[i] = (_Float16*)alloc(PLX * 2);
    _Float16* woT[2]; for (int i = 0; i < 2; ++i) woT[i] = (_Float16*)alloc((size_t)512 * 4096 * 2);
    const size_t WTE = (size_t)hcnt * 512 * 512;
    _Float16* wqT[2]; for (int i = 0; i < 2; ++i) wqT[i] = (_Float16*)alloc(WTE * 2);
    _Float16* wkT[2]; for (int i = 0; i < 2; ++i) wkT[i] = (_Float16*)alloc(WTE * 2);
    _Float16* wvT[2]; for (int i = 0; i < 2; ++i) wvT[i] = (_Float16*)alloc(WTE * 2);
    const size_t QZE = (size_t)Z * 1024 * 1024;
    _Float16* qz[2]; for (int i = 0; i < 2; ++i) qz[i] = (_Float16*)alloc(QZE * 2);
    _Float16* kz[2]; for (int i = 0; i < 2; ++i) kz[i] = (_Float16*)alloc(QZE * 2);
    float* S = (float*)alloc(QZE * 4);
    const size_t VTE = (size_t)Z * 512 * 1024;
    _Float16* vT[4]; for (int i = 0; i < 4; ++i) vT[i] = (_Float16*)alloc(VTE * 2);
    const size_t RCE = (size_t)2048 * 4096;
    _Float16* rcs[4];
    if (hcnt == 8) {
        // overlay on qz/kz (dead after scores; single chunk)
        for (int i = 0; i < 4; ++i) rcs[i] = (_Float16*)((char*)qz[0] + (size_t)i * RCE * 2);
    } else {
        for (int i = 0; i < 4; ++i) rcs[i] = (_Float16*)alloc(RCE * 2);
    }

    dim3 blk(256);

    encode_phasor<<<1024, blk, 0, stream>>>(query, xq[0], xq[1], xq[2], xq[3]);
    encode_phasor<<<1024, blk, 0, stream>>>(keyvalue, xk[0], xk[1], xk[2], xk[3]);
    tsplit64<<<dim3(64, 8, 1), blk, 0, stream>>>(wo, woT[0], woT[1], 4096, 512);

    for (int c = 0; c < 8 / hcnt; ++c) {
        const int h0 = c * hcnt;
        const float* wqc = wq + (size_t)h0 * 512 * 512;
        const float* wkc = wk + (size_t)h0 * 512 * 512;
        const float* wvc = wv + (size_t)h0 * 512 * 512;
        tsplit64<<<dim3(8, 8, hcnt), blk, 0, stream>>>(wqc, wqT[0], wqT[1], 512, 512);
        tsplit64<<<dim3(8, 8, hcnt), blk, 0, stream>>>(wkc, wkT[0], wkT[1], 512, 512);
        tsplit64<<<dim3(8, 8, hcnt), blk, 0, stream>>>(wvc, wvT[0], wvT[1], 512, 512);

        proj_mfma<false><<<dim3(32, 8 * hcnt), blk, 0, stream>>>(
            xq[0], xq[1], xq[2], xq[3], wqT[0], wqT[1], bq,
            qz[0], qz[1], nullptr, nullptr, nullptr, nullptr, h0, hcnt);
        proj_mfma<false><<<dim3(32, 8 * hcnt), blk, 0, stream>>>(
            xk[0], xk[1], xk[2], xk[3], wkT[0], wkT[1], bk,
            kz[0], kz[1], nullptr, nullptr, nullptr, nullptr, h0, hcnt);
        proj_mfma<true><<<dim3(32, 8 * hcnt), blk, 0, stream>>>(
            xk[0], xk[1], xk[2], xk[3], wvT[0], wvT[1], bv,
            nullptr, nullptr, vT[0], vT[1], vT[2], vT[3], h0, hcnt);

        scores_mfma<<<dim3(8, 8, Z), blk, 0, stream>>>(qz[0], qz[1], kz[0], kz[1], S);
        softmax_split<<<dim3(Z * 1024), blk, 0, stream>>>(S);
        pv_mfma<<<dim3(8, 8, Z), blk, 0, stream>>>(
            (const _Float16*)S, vT[0], vT[1], vT[2], vT[3],
            rcs[0], rcs[1], rcs[2], rcs[3], h0, hcnt);
    }

    final_mfma<<<dim3(32, 8), blk, 0, stream>>>(
        rcs[0], rcs[1], rcs[2], rcs[3], woT[0], woT[1], bo, out);
}

// Round 4
// 579.908 us; speedup vs baseline: 3.8477x; 1.0494x over previous
//
#include <hip/hip_runtime.h>
#include <math.h>

// Phasor attention via split-fp16 MFMA (fp16x2 error-free splitting, ~fp32 accuracy).
// B=2, T=1024, D=512, H=8.
// Round 4: all GEMMs on mfma_f32_32x32x16_f16 (2x FLOP per LDS byte vs 16x16x32),
// uniform 64KB-dbuf 2-blocks/CU structure, K-split final + combine, merged q/k proj,
// XCD-swizzled scores/pv grids.

#define PI_F 3.14159274101257324f

typedef __attribute__((ext_vector_type(8))) _Float16 half8;
typedef __attribute__((ext_vector_type(4))) _Float16 half4;
typedef __attribute__((ext_vector_type(2))) _Float16 half2v;
typedef __attribute__((ext_vector_type(16))) float f32x16;
typedef unsigned int u32;

#define MFMA32(a, b, c) __builtin_amdgcn_mfma_f32_32x32x16_f16((a), (b), (c), 0, 0, 0)
// C/D layout for 32x32: col = lane&31, row = (reg&3) + 8*(reg>>2) + 4*(lane>>5)
#define ROWOF(r, ln) (((r) & 3) + 8 * ((r) >> 2) + 4 * ((ln) >> 5))

__device__ __forceinline__ void gll16(const void* g, void* l) {
    __builtin_amdgcn_global_load_lds(
        (const __attribute__((address_space(1))) u32*)g,
        (__attribute__((address_space(3))) u32*)l, 16, 0, 0);
}

// LDS row format: 128B = 8x16B slots; logical slots 0-3 = hi plane (32 fp16 of k),
// 4-7 = lo plane; stored slot = logical ^ (row&7).  BK = 32.
#define MKSRC(U, NT, gh, gl, stride, sp, dp, dbase)                         \
    _Pragma("unroll") for (int u_ = 0; u_ < (U); ++u_) {                    \
        const int idx_ = u_ * (NT) + tid;                                   \
        const int row_ = idx_ >> 3, ss_ = idx_ & 7;                         \
        const int sl_ = ss_ ^ (row_ & 7);                                   \
        sp[u_] = ((sl_ < 4) ? (gh) : (gl)) + (size_t)row_ * (stride)        \
                 + (sl_ & 3) * 8;                                           \
        dp[u_] = (dbase) + idx_ * 16;                                       \
    }
#define STAGE(U, sp, dp, bufoff, kk)                                        \
    _Pragma("unroll") for (int u_ = 0; u_ < (U); ++u_)                      \
        gll16(sp[u_] + (kk), lds + (bufoff) + dp[u_]);

// Fragment read: 8 fp16 (k-octet oct in [0,4), hilo 0/1) with XOR de-swizzle.
__device__ __forceinline__ half8 fragP(const char* ldsp, int row, int oct, int hilo) {
    const int sl = (oct + hilo * 4) ^ (row & 7);
    return *(const half8*)(ldsp + row * 128 + (sl << 4));
}

__device__ __forceinline__ void split2(float x, _Float16& h, _Float16& l) {
    _Float16 hh = (_Float16)x;
    h = hh;
    l = (_Float16)((x - (float)hh) * 4096.0f);
}

// bijective XCD swizzle (nwg divisible by 8)
__device__ __forceinline__ int xcdswz(int bid, int nwg) {
    const int cpx = nwg >> 3;
    return (bid & 7) * cpx + (bid >> 3);
}

// ---------------------------------------------------------------------------
// encode: x [2048*512] f32 -> phasor planes cos/sin hi/lo [2048][512] fp16.
// ---------------------------------------------------------------------------
__global__ __launch_bounds__(256) void encode_phasor(
    const float* __restrict__ x,
    _Float16* __restrict__ ch, _Float16* __restrict__ cl,
    _Float16* __restrict__ sh, _Float16* __restrict__ sl)
{
    const int idx = blockIdx.x * 256 + threadIdx.x;
    float4 v = ((const float4*)x)[idx];
    float cc[4], ss[4];
    sincosf(PI_F * v.x, &ss[0], &cc[0]);
    sincosf(PI_F * v.y, &ss[1], &cc[1]);
    sincosf(PI_F * v.z, &ss[2], &cc[2]);
    sincosf(PI_F * v.w, &ss[3], &cc[3]);
    half4 chv, clv, shv, slv;
#pragma unroll
    for (int q = 0; q < 4; ++q) {
        _Float16 a, b;
        split2(cc[q], a, b); chv[q] = a; clv[q] = b;
        split2(ss[q], a, b); shv[q] = a; slv[q] = b;
    }
    ((half4*)ch)[idx] = chv;
    ((half4*)cl)[idx] = clv;
    ((half4*)sh)[idx] = shv;
    ((half4*)sl)[idx] = slv;
}

// ---------------------------------------------------------------------------
// tsplit64: w [h][K][N] f32 -> transposed split planes th/tl [h][N][K] fp16.
// ---------------------------------------------------------------------------
__global__ __launch_bounds__(256) void tsplit64(
    const float* __restrict__ w, _Float16* __restrict__ th, _Float16* __restrict__ tl,
    int K, int N)
{
    const int kt = blockIdx.x, ntile = blockIdx.y, h = blockIdx.z;
    const int k0 = kt * 64, n0 = ntile * 64;
    __shared__ float T[64][65];
    const int tid = threadIdx.x;
    const float* wb = w + (size_t)h * K * N;
    {
        const int r = tid >> 4, c4 = (tid & 15) * 4;
#pragma unroll
        for (int rr = 0; rr < 64; rr += 16) {
            float4 v = *(const float4*)&wb[(size_t)(k0 + rr + r) * N + n0 + c4];
            T[rr + r][c4 + 0] = v.x; T[rr + r][c4 + 1] = v.y;
            T[rr + r][c4 + 2] = v.z; T[rr + r][c4 + 3] = v.w;
        }
    }
    __syncthreads();
    {
        const int n = tid >> 2, kq = (tid & 3) * 16;
        half8 hv[2], lv[2];
#pragma unroll
        for (int q = 0; q < 16; ++q) {
            float f = T[kq + q][n];
            _Float16 hh, ll; split2(f, hh, ll);
            hv[q >> 3][q & 7] = hh; lv[q >> 3][q & 7] = ll;
        }
        _Float16* oh = th + ((size_t)h * N + n0 + n) * K + k0 + kq;
        _Float16* ol = tl + ((size_t)h * N + n0 + n) * K + k0 + kq;
        *(half8*)oh = hv[0]; *(half8*)(oh + 8) = hv[1];
        *(half8*)ol = lv[0]; *(half8*)(ol + 8) = lv[1];
    }
}

// ---------------------------------------------------------------------------
// proj_qk: y = phasor(x) @ w + bias -> normalize -> fp16 split phasors (c,s
// interleaved). Block 64x128, waves 2x2, wave-tile 32x64 (1x2 MFMA32), BK=32.
// blockIdx.z: 0 = query, 1 = key.
// ---------------------------------------------------------------------------
__global__ __launch_bounds__(256, 2) void proj_qk(
    const _Float16* __restrict__ qch, const _Float16* __restrict__ qcl,
    const _Float16* __restrict__ qsh, const _Float16* __restrict__ qsl,
    const _Float16* __restrict__ kch, const _Float16* __restrict__ kcl,
    const _Float16* __restrict__ ksh, const _Float16* __restrict__ ksl,
    const _Float16* __restrict__ wqh, const _Float16* __restrict__ wql,
    const _Float16* __restrict__ wkh, const _Float16* __restrict__ wkl,
    const float* __restrict__ bq, const float* __restrict__ bk,
    _Float16* __restrict__ qzh, _Float16* __restrict__ qzl,
    _Float16* __restrict__ kzh, _Float16* __restrict__ kzl,
    int h0, int hcnt)
{
    const int inp = blockIdx.z;
    const _Float16* xch = inp ? kch : qch;
    const _Float16* xcl = inp ? kcl : qcl;
    const _Float16* xsh = inp ? ksh : qsh;
    const _Float16* xsl = inp ? ksl : qsl;
    const _Float16* wth = inp ? wkh : wqh;
    const _Float16* wtl = inp ? wkl : wql;
    const float* bias = inp ? bk : bq;
    _Float16* ozh = inp ? kzh : qzh;
    _Float16* ozl = inp ? kzl : qzl;

    const int m0 = blockIdx.x * 64;
    const int hc = blockIdx.y >> 2;
    const int n0 = (blockIdx.y & 3) * 128;
    __shared__ char lds[65536];  // buf: [Xc 8K][Xs 8K][W 16K] x2
    const int tid = threadIdx.x, wv = tid >> 6, ln = tid & 63;
    const int wr = wv >> 1, wc = wv & 1, lm32 = ln & 31, lh = ln >> 5;

    const _Float16* sp_xc[2]; int dp_xc[2];
    const _Float16* sp_xs[2]; int dp_xs[2];
    const _Float16* sp_w[4];  int dp_w[4];
    MKSRC(2, 256, xch + (size_t)m0 * 512, xcl + (size_t)m0 * 512, 512, sp_xc, dp_xc, 0);
    MKSRC(2, 256, xsh + (size_t)m0 * 512, xsl + (size_t)m0 * 512, 512, sp_xs, dp_xs, 8192);
    const _Float16* wbh = wth + ((size_t)hc * 512 + n0) * 512;
    const _Float16* wbl = wtl + ((size_t)hc * 512 + n0) * 512;
    MKSRC(4, 256, wbh, wbl, 512, sp_w, dp_w, 16384);

    f32x16 ach[2] = {}, acl[2] = {}, ash[2] = {}, asl[2] = {};

    STAGE(2, sp_xc, dp_xc, 0, 0);
    STAGE(2, sp_xs, dp_xs, 0, 0);
    STAGE(4, sp_w,  dp_w,  0, 0);
    int off = 0;
    for (int s = 0; s < 16; ++s) {
        __syncthreads();
        const int nxt = off ^ 32768;
        if (s + 1 < 16) {
            const int kk = (s + 1) * 32;
            STAGE(2, sp_xc, dp_xc, nxt, kk);
            STAGE(2, sp_xs, dp_xs, nxt, kk);
            STAGE(4, sp_w,  dp_w,  nxt, kk);
        }
        const char* Xc = lds + off;
        const char* Xs = lds + off + 8192;
        const char* W  = lds + off + 16384;
        __builtin_amdgcn_s_setprio(1);
#pragma unroll
        for (int kw = 0; kw < 2; ++kw) {
            const int oct = kw * 2 + lh;
            half8 wh0 = fragP(W, wc * 64 + lm32, oct, 0);
            half8 wh1 = fragP(W, wc * 64 + 32 + lm32, oct, 0);
            half8 wl0 = fragP(W, wc * 64 + lm32, oct, 1);
            half8 wl1 = fragP(W, wc * 64 + 32 + lm32, oct, 1);
            half8 c1 = fragP(Xc, wr * 32 + lm32, oct, 0);
            half8 c2 = fragP(Xc, wr * 32 + lm32, oct, 1);
            half8 s1 = fragP(Xs, wr * 32 + lm32, oct, 0);
            half8 s2 = fragP(Xs, wr * 32 + lm32, oct, 1);
            ach[0] = MFMA32(c1, wh0, ach[0]);
            acl[0] = MFMA32(c1, wl0, acl[0]);
            acl[0] = MFMA32(c2, wh0, acl[0]);
            ash[0] = MFMA32(s1, wh0, ash[0]);
            asl[0] = MFMA32(s1, wl0, asl[0]);
            asl[0] = MFMA32(s2, wh0, asl[0]);
            ach[1] = MFMA32(c1, wh1, ach[1]);
            acl[1] = MFMA32(c1, wl1, acl[1]);
            acl[1] = MFMA32(c2, wh1, acl[1]);
            ash[1] = MFMA32(s1, wh1, ash[1]);
            asl[1] = MFMA32(s1, wl1, asl[1]);
            asl[1] = MFMA32(s2, wh1, asl[1]);
        }
        __builtin_amdgcn_s_setprio(0);
        off = nxt;
    }

    const float LS = 1.0f / 4096.0f;
    const int b = m0 >> 10, tbase = m0 & 1023;
    const size_t zz = (size_t)(b * hcnt + hc);
#pragma unroll
    for (int j = 0; j < 2; ++j) {
        const int nloc = wc * 64 + j * 32 + lm32;
        const float bval = bias[(size_t)(h0 + hc) * 512 + n0 + nloc];
#pragma unroll
        for (int r = 0; r < 16; ++r) {
            const int mloc = wr * 32 + ROWOF(r, ln);
            float yc = ach[j][r] + acl[j][r] * LS + bval;
            float ys = ash[j][r] + asl[j][r] * LS;
            float inv = 1.0f / sqrtf(fmaxf(yc * yc + ys * ys, 1e-36f));
            float c = yc * inv, sn = ys * inv;
            _Float16 chh, chl, shh, shl;
            split2(c, chh, chl); split2(sn, shh, shl);
            const size_t offo = (zz * 1024 + tbase + mloc) * 1024 + 2 * (n0 + nloc);
            half2v hv, lv;
            hv[0] = chh; hv[1] = shh; lv[0] = chl; lv[1] = shl;
            *(half2v*)(ozh + offo) = hv;
            *(half2v*)(ozl + offo) = lv;
        }
    }
}

// ---------------------------------------------------------------------------
// proj_v: same GEMM, epilogue writes transposed vT planes [Z][512 d][1024 t]
// via 2-round LDS transpose. Block 64x128 (m=t 64, n=d 128).
// ---------------------------------------------------------------------------
__global__ __launch_bounds__(256, 2) void proj_v(
    const _Float16* __restrict__ xch, const _Float16* __restrict__ xcl,
    const _Float16* __restrict__ xsh, const _Float16* __restrict__ xsl,
    const _Float16* __restrict__ wth, const _Float16* __restrict__ wtl,
    const float* __restrict__ bias,
    _Float16* __restrict__ vch, _Float16* __restrict__ vcl,
    _Float16* __restrict__ vsh, _Float16* __restrict__ vsl,
    int h0, int hcnt)
{
    const int m0 = blockIdx.x * 64;
    const int hc = blockIdx.y >> 2;
    const int n0 = (blockIdx.y & 3) * 128;
    __shared__ char lds[65536];
    const int tid = threadIdx.x, wv = tid >> 6, ln = tid & 63;
    const int wr = wv >> 1, wc = wv & 1, lm32 = ln & 31, lh = ln >> 5;

    const _Float16* sp_xc[2]; int dp_xc[2];
    const _Float16* sp_xs[2]; int dp_xs[2];
    const _Float16* sp_w[4];  int dp_w[4];
    MKSRC(2, 256, xch + (size_t)m0 * 512, xcl + (size_t)m0 * 512, 512, sp_xc, dp_xc, 0);
    MKSRC(2, 256, xsh + (size_t)m0 * 512, xsl + (size_t)m0 * 512, 512, sp_xs, dp_xs, 8192);
    const _Float16* wbh = wth + ((size_t)hc * 512 + n0) * 512;
    const _Float16* wbl = wtl + ((size_t)hc * 512 + n0) * 512;
    MKSRC(4, 256, wbh, wbl, 512, sp_w, dp_w, 16384);

    f32x16 ach[2] = {}, acl[2] = {}, ash[2] = {}, asl[2] = {};

    STAGE(2, sp_xc, dp_xc, 0, 0);
    STAGE(2, sp_xs, dp_xs, 0, 0);
    STAGE(4, sp_w,  dp_w,  0, 0);
    int off = 0;
    for (int s = 0; s < 16; ++s) {
        __syncthreads();
        const int nxt = off ^ 32768;
        if (s + 1 < 16) {
            const int kk = (s + 1) * 32;
            STAGE(2, sp_xc, dp_xc, nxt, kk);
            STAGE(2, sp_xs, dp_xs, nxt, kk);
            STAGE(4, sp_w,  dp_w,  nxt, kk);
        }
        const char* Xc = lds + off;
        const char* Xs = lds + off + 8192;
        const char* W  = lds + off + 16384;
        __builtin_amdgcn_s_setprio(1);
#pragma unroll
        for (int kw = 0; kw < 2; ++kw) {
            const int oct = kw * 2 + lh;
            half8 wh0 = fragP(W, wc * 64 + lm32, oct, 0);
            half8 wh1 = fragP(W, wc * 64 + 32 + lm32, oct, 0);
            half8 wl0 = fragP(W, wc * 64 + lm32, oct, 1);
            half8 wl1 = fragP(W, wc * 64 + 32 + lm32, oct, 1);
            half8 c1 = fragP(Xc, wr * 32 + lm32, oct, 0);
            half8 c2 = fragP(Xc, wr * 32 + lm32, oct, 1);
            half8 s1 = fragP(Xs, wr * 32 + lm32, oct, 0);
            half8 s2 = fragP(Xs, wr * 32 + lm32, oct, 1);
            ach[0] = MFMA32(c1, wh0, ach[0]);
            acl[0] = MFMA32(c1, wl0, acl[0]);
            acl[0] = MFMA32(c2, wh0, acl[0]);
            ash[0] = MFMA32(s1, wh0, ash[0]);
            asl[0] = MFMA32(s1, wl0, asl[0]);
            asl[0] = MFMA32(s2, wh0, asl[0]);
            ach[1] = MFMA32(c1, wh1, ach[1]);
            acl[1] = MFMA32(c1, wl1, acl[1]);
            acl[1] = MFMA32(c2, wh1, acl[1]);
            ash[1] = MFMA32(s1, wh1, ash[1]);
            asl[1] = MFMA32(s1, wl1, asl[1]);
            asl[1] = MFMA32(s2, wh1, asl[1]);
        }
        __builtin_amdgcn_s_setprio(0);
        off = nxt;
    }

    const float LS = 1.0f / 4096.0f;
    const int b = m0 >> 10, tbase = m0 & 1023;
    const size_t zz = (size_t)(b * hcnt + hc);
    _Float16* T = (_Float16*)lds;
    // 2 rounds: round 0 -> (c_hi, c_lo), round 1 -> (s_hi, s_lo).
#pragma unroll
    for (int round = 0; round < 2; ++round) {
        __syncthreads();
#pragma unroll
        for (int j = 0; j < 2; ++j) {
            const int dloc = wc * 64 + j * 32 + lm32;
            const float bval = bias[(size_t)(h0 + hc) * 512 + n0 + dloc];
#pragma unroll
            for (int r = 0; r < 16; ++r) {
                const int tloc = wr * 32 + ROWOF(r, ln);
                float yc = ach[j][r] + acl[j][r] * LS + bval;
                float ys = ash[j][r] + asl[j][r] * LS;
                float inv = 1.0f / sqrtf(fmaxf(yc * yc + ys * ys, 1e-36f));
                float val = (round ? ys : yc) * inv;
                _Float16 hh, ll;
                split2(val, hh, ll);
                T[dloc * 72 + tloc] = hh;
                T[9216 + dloc * 72 + tloc] = ll;
            }
        }
        __syncthreads();
        {
            const int p2 = tid >> 7, d = tid & 127;
            const _Float16* src = T + p2 * 9216 + d * 72;
            _Float16* plane = (round == 0) ? (p2 ? vcl : vch) : (p2 ? vsl : vsh);
            _Float16* dst = plane + (zz * 512 + n0 + d) * 1024 + tbase;
#pragma unroll
            for (int q = 0; q < 8; ++q)
                *(half8*)(dst + q * 8) = *(const half8*)(src + q * 8);
        }
    }
}

// ---------------------------------------------------------------------------
// scores: S[z][t][T] = (qz . kz)/512, K=1024 (c,s interleaved).
// Block 128x128, waves 2x2, wave-tile 64x64 (2x2 MFMA32), BK=32. XCD-swizzled.
// ---------------------------------------------------------------------------
__global__ __launch_bounds__(256, 2) void scores_mfma(
    const _Float16* __restrict__ qzh, const _Float16* __restrict__ qzl,
    const _Float16* __restrict__ kzh, const _Float16* __restrict__ kzl,
    float* __restrict__ S, int Z)
{
    const int wg = xcdswz(blockIdx.x, Z * 64);
    const int z = wg >> 6;
    const int rem = wg & 63;
    const int m0 = (rem & 7) << 7, n0 = (rem >> 3) << 7;
    __shared__ char lds[65536];  // buf: [A 16K][B 16K] x2
    const size_t zb = (size_t)z << 20;
    const int tid = threadIdx.x, wv = tid >> 6, ln = tid & 63;
    const int wr = wv >> 1, wc = wv & 1, lm32 = ln & 31, lh = ln >> 5;

    const _Float16* sp_a[4]; int dp_a[4];
    const _Float16* sp_b[4]; int dp_b[4];
    MKSRC(4, 256, qzh + zb + (size_t)m0 * 1024, qzl + zb + (size_t)m0 * 1024, 1024, sp_a, dp_a, 0);
    MKSRC(4, 256, kzh + zb + (size_t)n0 * 1024, kzl + zb + (size_t)n0 * 1024, 1024, sp_b, dp_b, 16384);

    f32x16 acch[2][2] = {}, accl[2][2] = {};

    STAGE(4, sp_a, dp_a, 0, 0);
    STAGE(4, sp_b, dp_b, 0, 0);
    int off = 0;
    for (int s = 0; s < 32; ++s) {
        __syncthreads();
        const int nxt = off ^ 32768;
        if (s + 1 < 32) {
            const int kk = (s + 1) * 32;
            STAGE(4, sp_a, dp_a, nxt, kk);
            STAGE(4, sp_b, dp_b, nxt, kk);
        }
        const char* A  = lds + off;
        const char* Bb = lds + off + 16384;
        __builtin_amdgcn_s_setprio(1);
#pragma unroll
        for (int kw = 0; kw < 2; ++kw) {
            const int oct = kw * 2 + lh;
            half8 bh0 = fragP(Bb, wc * 64 + lm32, oct, 0);
            half8 bh1 = fragP(Bb, wc * 64 + 32 + lm32, oct, 0);
            half8 bl0 = fragP(Bb, wc * 64 + lm32, oct, 1);
            half8 bl1 = fragP(Bb, wc * 64 + 32 + lm32, oct, 1);
#pragma unroll
            for (int i = 0; i < 2; ++i) {
                half8 qh = fragP(A, wr * 64 + i * 32 + lm32, oct, 0);
                half8 ql = fragP(A, wr * 64 + i * 32 + lm32, oct, 1);
                acch[i][0] = MFMA32(qh, bh0, acch[i][0]);
                accl[i][0] = MFMA32(qh, bl0, accl[i][0]);
                accl[i][0] = MFMA32(ql, bh0, accl[i][0]);
                acch[i][1] = MFMA32(qh, bh1, acch[i][1]);
                accl[i][1] = MFMA32(qh, bl1, accl[i][1]);
                accl[i][1] = MFMA32(ql, bh1, accl[i][1]);
            }
        }
        __builtin_amdgcn_s_setprio(0);
        off = nxt;
    }
    const float LS = 1.0f / 4096.0f, SC = 1.0f / 512.0f;
#pragma unroll
    for (int i = 0; i < 2; ++i)
#pragma unroll
        for (int j = 0; j < 2; ++j)
#pragma unroll
            for (int r = 0; r < 16; ++r) {
                const int row = m0 + wr * 64 + i * 32 + ROWOF(r, ln);
                const int col = n0 + wc * 64 + j * 32 + lm32;
                S[zb + (size_t)row * 1024 + col] =
                    (acch[i][j][r] + accl[i][j][r] * LS) * SC;
            }
}

// ---------------------------------------------------------------------------
// softmax rows of 1024 (max-subtracted); write P fp16 hi/lo split in place.
// ---------------------------------------------------------------------------
__global__ __launch_bounds__(256) void softmax_split(float* __restrict__ S)
{
    const size_t row = blockIdx.x;
    float* p = S + row * 1024;
    const int tid = threadIdx.x;
    float4 v = ((const float4*)p)[tid];
    float m = fmaxf(fmaxf(v.x, v.y), fmaxf(v.z, v.w));
#pragma unroll
    for (int off = 32; off >= 1; off >>= 1)
        m = fmaxf(m, __shfl_xor(m, off));
    __shared__ float redm[4], reds[4];
    const int wid = tid >> 6, lane = tid & 63;
    if (lane == 0) redm[wid] = m;
    __syncthreads();
    m = fmaxf(fmaxf(redm[0], redm[1]), fmaxf(redm[2], redm[3]));
    float4 e;
    e.x = expf(v.x - m); e.y = expf(v.y - m);
    e.z = expf(v.z - m); e.w = expf(v.w - m);
    float s = (e.x + e.y) + (e.z + e.w);
#pragma unroll
    for (int off = 32; off >= 1; off >>= 1)
        s += __shfl_xor(s, off);
    if (lane == 0) reds[wid] = s;
    __syncthreads();
    s = (reds[0] + reds[1]) + (reds[2] + reds[3]);
    e.x /= s; e.y /= s; e.z /= s; e.w /= s;
    __syncthreads();
    _Float16* ph = (_Float16*)p;
    half4 hv, lv;
    _Float16 a, b;
    split2(e.x, a, b); hv[0] = a; lv[0] = b;
    split2(e.y, a, b); hv[1] = a; lv[1] = b;
    split2(e.z, a, b); hv[2] = a; lv[2] = b;
    split2(e.w, a, b); hv[3] = a; lv[3] = b;
    *(half4*)(ph + tid * 4) = hv;
    *(half4*)(ph + 1024 + tid * 4) = lv;
}

// ---------------------------------------------------------------------------
// pv: out[z][t][d] = sum_T P[t][T]*vz[T][d], normalize, split, write rcs planes
// [2048][4096]. Block 128x64, waves 2x2, wave-tile 64x32 (2x1), BK=32. Swizzled.
// ---------------------------------------------------------------------------
__global__ __launch_bounds__(256, 2) void pv_mfma(
    const _Float16* __restrict__ P,
    const _Float16* __restrict__ vch, const _Float16* __restrict__ vcl,
    const _Float16* __restrict__ vsh, const _Float16* __restrict__ vsl,
    _Float16* __restrict__ rch, _Float16* __restrict__ rcl,
    _Float16* __restrict__ rsh, _Float16* __restrict__ rsl,
    int h0, int hcnt, int Z)
{
    const int wg = xcdswz(blockIdx.x, Z * 64);
    const int z = wg >> 6;
    const int rem = wg & 63;
    const int m0 = (rem & 7) << 7, n0 = (rem >> 3) << 6;
    __shared__ char lds[65536];  // buf: [P 16K][Vc 8K][Vs 8K] x2
    const int tid = threadIdx.x, wv = tid >> 6, ln = tid & 63;
    const int wr = wv >> 1, wc = wv & 1, lm32 = ln & 31, lh = ln >> 5;

    const _Float16* Pb = P + (size_t)z * 1024 * 2048 + (size_t)m0 * 2048;
    const size_t vb = (size_t)z * 512 * 1024 + (size_t)n0 * 1024;
    const _Float16* sp_p[4];  int dp_p[4];
    const _Float16* sp_vc[2]; int dp_vc[2];
    const _Float16* sp_vs[2]; int dp_vs[2];
    MKSRC(4, 256, Pb, Pb + 1024, 2048, sp_p, dp_p, 0);
    MKSRC(2, 256, vch + vb, vcl + vb, 1024, sp_vc, dp_vc, 16384);
    MKSRC(2, 256, vsh + vb, vsl + vb, 1024, sp_vs, dp_vs, 24576);

    f32x16 ac_h[2] = {}, ac_l[2] = {}, as_h[2] = {}, as_l[2] = {};

    STAGE(4, sp_p,  dp_p,  0, 0);
    STAGE(2, sp_vc, dp_vc, 0, 0);
    STAGE(2, sp_vs, dp_vs, 0, 0);
    int off = 0;
    for (int s = 0; s < 32; ++s) {
        __syncthreads();
        const int nxt = off ^ 32768;
        if (s + 1 < 32) {
            const int kk = (s + 1) * 32;
            STAGE(4, sp_p,  dp_p,  nxt, kk);
            STAGE(2, sp_vc, dp_vc, nxt, kk);
            STAGE(2, sp_vs, dp_vs, nxt, kk);
        }
        const char* A  = lds + off;
        const char* Vc = lds + off + 16384;
        const char* Vs = lds + off + 24576;
        __builtin_amdgcn_s_setprio(1);
#pragma unroll
        for (int kw = 0; kw < 2; ++kw) {
            const int oct = kw * 2 + lh;
            half8 vc1 = fragP(Vc, wc * 32 + lm32, oct, 0);
            half8 vc2 = fragP(Vc, wc * 32 + lm32, oct, 1);
            half8 vs1 = fragP(Vs, wc * 32 + lm32, oct, 0);
            half8 vs2 = fragP(Vs, wc * 32 + lm32, oct, 1);
#pragma unroll
            for (int i = 0; i < 2; ++i) {
                half8 ph = fragP(A, wr * 64 + i * 32 + lm32, oct, 0);
                half8 pl = fragP(A, wr * 64 + i * 32 + lm32, oct, 1);
                ac_h[i] = MFMA32(ph, vc1, ac_h[i]);
                ac_l[i] = MFMA32(ph, vc2, ac_l[i]);
                ac_l[i] = MFMA32(pl, vc1, ac_l[i]);
                as_h[i] = MFMA32(ph, vs1, as_h[i]);
                as_l[i] = MFMA32(ph, vs2, as_l[i]);
                as_l[i] = MFMA32(pl, vs1, as_l[i]);
            }
        }
        __builtin_amdgcn_s_setprio(0);
        off = nxt;
    }
    const float LS = 1.0f / 4096.0f;
    const int b = z / hcnt, hg = h0 + z % hcnt;
#pragma unroll
    for (int i = 0; i < 2; ++i)
#pragma unroll
        for (int r = 0; r < 16; ++r) {
            const int t = m0 + wr * 64 + i * 32 + ROWOF(r, ln);
            const int d = n0 + wc * 32 + lm32;
            float zc = ac_h[i][r] + ac_l[i][r] * LS;
            float zs = as_h[i][r] + as_l[i][r] * LS;
            float inv = 1.0f / sqrtf(fmaxf(zc * zc + zs * zs, 1e-36f));
            float c = zc * inv, sn = zs * inv;
            _Float16 chh, chl, shh, shl;
            split2(c, chh, chl); split2(sn, shh, shl);
            const size_t offo = ((size_t)(b * 1024 + t)) * 4096 + (size_t)hg * 512 + d;
            rch[offo] = chh; rcl[offo] = chl; rsh[offo] = shh; rsl[offo] = shl;
        }
}

// ---------------------------------------------------------------------------
// final (K-split): partial z = rz @ wo over K range [ks*1024, +1024).
// Block 64x128, waves 2x2, wave-tile 32x64 (1x2), BK=32. Writes f32 (zr,zi).
// ---------------------------------------------------------------------------
__global__ __launch_bounds__(256, 2) void final_mfma(
    const _Float16* __restrict__ rch, const _Float16* __restrict__ rcl,
    const _Float16* __restrict__ rsh, const _Float16* __restrict__ rsl,
    const _Float16* __restrict__ woh, const _Float16* __restrict__ wol,
    float* __restrict__ pbuf)
{
    const int m0 = blockIdx.x * 64, n0 = blockIdx.y * 128;
    const int ks = blockIdx.z;
    const size_t kbase = (size_t)ks * 1024;
    __shared__ char lds[65536];  // buf: [Rc 8K][Rs 8K][Wo 16K] x2
    const int tid = threadIdx.x, wv = tid >> 6, ln = tid & 63;
    const int wr = wv >> 1, wc = wv & 1, lm32 = ln & 31, lh = ln >> 5;

    const _Float16* sp_rc[2]; int dp_rc[2];
    const _Float16* sp_rs[2]; int dp_rs[2];
    const _Float16* sp_w[4];  int dp_w[4];
    MKSRC(2, 256, rch + (size_t)m0 * 4096 + kbase, rcl + (size_t)m0 * 4096 + kbase, 4096, sp_rc, dp_rc, 0);
    MKSRC(2, 256, rsh + (size_t)m0 * 4096 + kbase, rsl + (size_t)m0 * 4096 + kbase, 4096, sp_rs, dp_rs, 8192);
    MKSRC(4, 256, woh + (size_t)n0 * 4096 + kbase, wol + (size_t)n0 * 4096 + kbase, 4096, sp_w, dp_w, 16384);

    f32x16 rr_h[2] = {}, rr_l[2] = {}, ri_h[2] = {}, ri_l[2] = {};

    STAGE(2, sp_rc, dp_rc, 0, 0);
    STAGE(2, sp_rs, dp_rs, 0, 0);
    STAGE(4, sp_w,  dp_w,  0, 0);
    int off = 0;
    for (int s = 0; s < 32; ++s) {
        __syncthreads();
        const int nxt = off ^ 32768;
        if (s + 1 < 32) {
            const int kk = (s + 1) * 32;
            STAGE(2, sp_rc, dp_rc, nxt, kk);
            STAGE(2, sp_rs, dp_rs, nxt, kk);
            STAGE(4, sp_w,  dp_w,  nxt, kk);
        }
        const char* Rc = lds + off;
        const char* Rs = lds + off + 8192;
        const char* W  = lds + off + 16384;
        __builtin_amdgcn_s_setprio(1);
#pragma unroll
        for (int kw = 0; kw < 2; ++kw) {
            const int oct = kw * 2 + lh;
            half8 wh0 = fragP(W, wc * 64 + lm32, oct, 0);
            half8 wh1 = fragP(W, wc * 64 + 32 + lm32, oct, 0);
            half8 wl0 = fragP(W, wc * 64 + lm32, oct, 1);
            half8 wl1 = fragP(W, wc * 64 + 32 + lm32, oct, 1);
            half8 c1 = fragP(Rc, wr * 32 + lm32, oct, 0);
            half8 c2 = fragP(Rc, wr * 32 + lm32, oct, 1);
            half8 s1 = fragP(Rs, wr * 32 + lm32, oct, 0);
            half8 s2 = fragP(Rs, wr * 32 + lm32, oct, 1);
            rr_h[0] = MFMA32(c1, wh0, rr_h[0]);
            rr_l[0] = MFMA32(c1, wl0, rr_l[0]);
            rr_l[0] = MFMA32(c2, wh0, rr_l[0]);
            ri_h[0] = MFMA32(s1, wh0, ri_h[0]);
            ri_l[0] = MFMA32(s1, wl0, ri_l[0]);
            ri_l[0] = MFMA32(s2, wh0, ri_l[0]);
            rr_h[1] = MFMA32(c1, wh1, rr_h[1]);
            rr_l[1] = MFMA32(c1, wl1, rr_l[1]);
            rr_l[1] = MFMA32(c2, wh1, rr_l[1]);
            ri_h[1] = MFMA32(s1, wh1, ri_h[1]);
            ri_l[1] = MFMA32(s1, wl1, ri_l[1]);
            ri_l[1] = MFMA32(s2, wh1, ri_l[1]);
        }
        __builtin_amdgcn_s_setprio(0);
        off = nxt;
    }
    const float LS = 1.0f / 4096.0f;
#pragma unroll
    for (int j = 0; j < 2; ++j) {
        const int ng = n0 + wc * 64 + j * 32 + lm32;
#pragma unroll
        for (int r = 0; r < 16; ++r) {
            const int mg = m0 + wr * 32 + ROWOF(r, ln);
            float zr = rr_h[j][r] + rr_l[j][r] * LS;
            float zi = ri_h[j][r] + ri_l[j][r] * LS;
            float2 v; v.x = zr; v.y = zi;
            *(float2*)&pbuf[((size_t)(ks * 2048 + mg) * 512 + ng) * 2] = v;
        }
    }
}

// ---------------------------------------------------------------------------
// combine: out[m][n] = atan2(sum zi, sum zr + bo[n]) / pi
// ---------------------------------------------------------------------------
__global__ __launch_bounds__(256) void final_combine(
    const float* __restrict__ pbuf, const float* __restrict__ bo,
    float* __restrict__ out, int KS)
{
    const int m = blockIdx.x, t = threadIdx.x;
    float4 acc = {0.f, 0.f, 0.f, 0.f};
    for (int s = 0; s < KS; ++s) {
        float4 v = *(const float4*)&pbuf[(size_t)(s * 2048 + m) * 1024 + t * 4];
        acc.x += v.x; acc.y += v.y; acc.z += v.z; acc.w += v.w;
    }
    const int n0 = t * 2;
    out[(size_t)m * 512 + n0]     = atan2f(acc.y, acc.x + bo[n0]) / PI_F;
    out[(size_t)m * 512 + n0 + 1] = atan2f(acc.w, acc.z + bo[n0 + 1]) / PI_F;
}

// ---------------------------------------------------------------------------
extern "C" void kernel_launch(void* const* d_in, const int* in_sizes, int n_in,
                              void* d_out, int out_size, void* d_ws, size_t ws_size,
                              hipStream_t stream)
{
    (void)in_sizes; (void)n_in; (void)out_size;
    const float* query    = (const float*)d_in[0];
    const float* keyvalue = (const float*)d_in[1];
    const float* wq = (const float*)d_in[2];
    const float* bq = (const float*)d_in[3];
    const float* wk = (const float*)d_in[4];
    const float* bk = (const float*)d_in[5];
    const float* wv = (const float*)d_in[6];
    const float* bv = (const float*)d_in[7];
    const float* wo = (const float*)d_in[8];
    const float* bo = (const float*)d_in[9];
    float* out = (float*)d_out;

    // memory tiers: hcnt=8 ~304MB (rcs overlays qz); 4 ~228MB; 2 ~158MB.
    int hcnt;
    if (ws_size >= (size_t)320 * 1024 * 1024) hcnt = 8;
    else if (ws_size >= (size_t)240 * 1024 * 1024) hcnt = 4;
    else hcnt = 2;
    const int Z = 2 * hcnt;
    const int KS = (hcnt == 2) ? 2 : 4;  // pbuf (KS*8MB) overlays kz (4Z MB)

    char* p = (char*)d_ws;
    auto alloc = [&](size_t bytes) {
        char* r = p;
        p += (bytes + 255) & ~(size_t)255;
        return r;
    };
    const size_t PLX = (size_t)2048 * 512;
    _Float16* xq[4]; for (int i = 0; i < 4; ++i) xq[i] = (_Float16*)alloc(PLX * 2);
    _Float16* xk[4]; for (int i = 0; i < 4; ++i) xk[i] = (_Float16*)alloc(PLX * 2);
    _Float16* woT[2]; for (int i = 0; i < 2; ++i) woT[i] = (_Float16*)alloc((size_t)512 * 4096 * 2);
    const size_t WTE = (size_t)hcnt * 512 * 512;
    _Float16* wqT[2]; for (int i = 0; i < 2; ++i) wqT[i] = (_Float16*)alloc(WTE * 2);
    _Float16* wkT[2]; for (int i = 0; i < 2; ++i) wkT[i] = (_Float16*)alloc(WTE * 2);
    _Float16* wvT[2]; for (int i = 0; i < 2; ++i) wvT[i] = (_Float16*)alloc(WTE * 2);
    const size_t QZE = (size_t)Z * 1024 * 1024;
    _Float16* qz[2]; for (int i = 0; i < 2; ++i) qz[i] = (_Float16*)alloc(QZE * 2);
    _Float16* kz[2]; for (int i = 0; i < 2; ++i) kz[i] = (_Float16*)alloc(QZE * 2);
    float* S = (float*)alloc(QZE * 4);
    const size_t VTE = (size_t)Z * 512 * 1024;
    _Float16* vT[4]; for (int i = 0; i < 4; ++i) vT[i] = (_Float16*)alloc(VTE * 2);
    const size_t RCE = (size_t)2048 * 4096;
    _Float16* rcs[4];
    if (hcnt == 8) {
        for (int i = 0; i < 4; ++i) rcs[i] = (_Float16*)((char*)qz[0] + (size_t)i * RCE * 2);
    } else {
        for (int i = 0; i < 4; ++i) rcs[i] = (_Float16*)alloc(RCE * 2);
    }
    float* pbuf = (float*)kz[0];  // kz dead after scores of last chunk

    dim3 blk(256);

    encode_phasor<<<1024, blk, 0, stream>>>(query, xq[0], xq[1], xq[2], xq[3]);
    encode_phasor<<<1024, blk, 0, stream>>>(keyvalue, xk[0], xk[1], xk[2], xk[3]);
    tsplit64<<<dim3(64, 8, 1), blk, 0, stream>>>(wo, woT[0], woT[1], 4096, 512);

    for (int c = 0; c < 8 / hcnt; ++c) {
        const int h0 = c * hcnt;
        const float* wqc = wq + (size_t)h0 * 512 * 512;
        const float* wkc = wk + (size_t)h0 * 512 * 512;
        const float* wvc = wv + (size_t)h0 * 512 * 512;
        tsplit64<<<dim3(8, 8, hcnt), blk, 0, stream>>>(wqc, wqT[0], wqT[1], 512, 512);
        tsplit64<<<dim3(8, 8, hcnt), blk, 0, stream>>>(wkc, wkT[0], wkT[1], 512, 512);
        tsplit64<<<dim3(8, 8, hcnt), blk, 0, stream>>>(wvc, wvT[0], wvT[1], 512, 512);

        proj_qk<<<dim3(32, 4 * hcnt, 2), blk, 0, stream>>>(
            xq[0], xq[1], xq[2], xq[3], xk[0], xk[1], xk[2], xk[3],
            wqT[0], wqT[1], wkT[0], wkT[1], bq, bk,
            qz[0], qz[1], kz[0], kz[1], h0, hcnt);
        proj_v<<<dim3(32, 4 * hcnt), blk, 0, stream>>>(
            xk[0], xk[1], xk[2], xk[3], wvT[0], wvT[1], bv,
            vT[0], vT[1], vT[2], vT[3], h0, hcnt);

        scores_mfma<<<dim3(Z * 64), blk, 0, stream>>>(qz[0], qz[1], kz[0], kz[1], S, Z);
        softmax_split<<<dim3(Z * 1024), blk, 0, stream>>>(S);
        pv_mfma<<<dim3(Z * 64), blk, 0, stream>>>(
            (const _Float16*)S, vT[0], vT[1], vT[2], vT[3],
            rcs[0], rcs[1], rcs[2], rcs[3], h0, hcnt, Z);
    }

    final_mfma<<<dim3(32, 4, KS), blk, 0, stream>>>(
        rcs[0], rcs[1], rcs[2], rcs[3], woT[0], woT[1], pbuf);
    final_combine<<<dim3(2048), blk, 0, stream>>>(pbuf, bo, out, KS);
}